// Round 8
// baseline (642.525 us; speedup 1.0000x reference)
//
#include <hip/hip_runtime.h>

// ---- problem constants ----
#define Hdim   3584
#define NH     28
#define NKV    4
#define HD     128
#define Sq     2048
#define NQKV   4608          // 3584 q + 512 k + 512 v
#define KD     3584          // inner dim of both GEMMs

typedef unsigned short u16;
typedef unsigned int   u32;
typedef _Float16 f16;
typedef _Float16 f16x8 __attribute__((ext_vector_type(8)));     // MFMA A/B operand (4 VGPRs)
typedef unsigned short u16x8 __attribute__((ext_vector_type(8)));
typedef float f32x4 __attribute__((ext_vector_type(4)));        // MFMA C/D operand

__device__ __forceinline__ u16 f2h(float x) { f16 h = (f16)x; return __builtin_bit_cast(u16, h); }
__device__ __forceinline__ float h2f(u16 b) { return (float)__builtin_bit_cast(f16, b); }
__device__ __forceinline__ void split2(float x, u16& hi, u16& lo) {
    hi = f2h(x);
    lo = f2h(x - h2f(hi));   // combined ~22-bit mantissa
}

// async global->LDS, 16B per lane; LDS dest = wave-uniform base + lane*16
#define GLL16(gp, lp) __builtin_amdgcn_global_load_lds( \
    (__attribute__((address_space(1))) void*)(gp),      \
    (__attribute__((address_space(3))) void*)(lp), 16, 0, 0)

// ---- fp32 -> fp16, 8 elems/thread ----
__global__ void k_cvt(const float* __restrict__ x, u16* __restrict__ yh, int n8) {
    int i = blockIdx.x * 256 + threadIdx.x;
    if (i >= n8) return;
    const float4* p = (const float4*)(x + (size_t)i * 8);
    float4 a = p[0], b = p[1];
    float v[8] = {a.x, a.y, a.z, a.w, b.x, b.y, b.z, b.w};
    u16x8 h;
#pragma unroll
    for (int j = 0; j < 8; ++j) h[j] = f2h(v[j]);
    *(u16x8*)(yh + (size_t)i * 8) = h;
}

// ---- concat biases (q|k|v) ----
__global__ void k_bias(const float* __restrict__ bq, const float* __restrict__ bk,
                       const float* __restrict__ bv, float* __restrict__ out) {
    int i = blockIdx.x * 256 + threadIdx.x;
    if (i >= NQKV) return;
    out[i] = (i < 3584) ? bq[i] : (i < 4096 ? bk[i - 3584] : bv[i - 4096]);
}

// ---- AWQ int4 dequant -> W (dout x KD) fp16 --- tiled LDS transpose ----
// R7: coalesced qw staging into LDS removed the stride-1792B gather that was
// hiding ~100us below the top-5 cutoff.
__global__ __launch_bounds__(256) void k_dequant(const int* __restrict__ qw,
                                                 const int* __restrict__ qz,
                                                 const float* __restrict__ sc,
                                                 u16* __restrict__ W, int dout) {
    __shared__ u32 L[64][9];       // 64 rows x 8 words (+1 pad: breaks bank resonance)
    __shared__ float scl[64];
    __shared__ u32 zq[8];
    int tid = threadIdx.x;
    int w8 = dout >> 3;
    int c0 = blockIdx.x * 64, j0 = blockIdx.x * 8;
    int r0 = blockIdx.y * 64, g = r0 >> 7;       // G=128, r0%128 in {0,64} -> uniform
#pragma unroll
    for (int t = 0; t < 2; ++t) {
        int u = tid + t * 256;
        int rr = u >> 3, jj = u & 7;             // coalesced: 8 consecutive words/row
        L[rr][jj] = (u32)qw[(size_t)(r0 + rr) * w8 + j0 + jj];
    }
    if (tid < 64) scl[tid] = sc[(size_t)g * dout + c0 + tid];
    if (tid < 8)  zq[tid]  = (u32)qz[(size_t)g * w8 + j0 + tid];
    __syncthreads();
#pragma unroll
    for (int t = 0; t < 2; ++t) {
        int u = tid + t * 256;
        int lc = u >> 3, r8 = (u & 7) << 3;      // chunk: col c0+lc, rows r0+r8..+7
        int sh = (lc & 7) << 2, jc = lc >> 3;
        int z = (int)((zq[jc] >> sh) & 15u);
        float s = scl[lc];
        u16x8 v;
#pragma unroll
        for (int i = 0; i < 8; ++i) {
            int w = (int)((L[r8 + i][jc] >> sh) & 15u);
            v[i] = f2h((float)(w - z) * s);
        }
        *(u16x8*)(W + (size_t)(c0 + lc) * KD + r0 + r8) = v;
    }
}

// ---- fp16 MFMA GEMM (m97-style + T2 XOR-swizzle): C = A @ B^T + bias ----
// T2: 128B LDS row stride = 32 banks -> chunk16B ^= row&7 on BOTH sides.
// Measured R4: SQ_LDS_BANK_CONFLICT = 0.
// R6 lesson: XCD-chunked blockIdx remap INCREASED FETCH 124->183MB; linear
// order already time-shares one A-panel across XCDs via L3. Keep linear.
__global__ __launch_bounds__(256) void k_gemm_f16(const u16* __restrict__ A,
                                                  const u16* __restrict__ B,
                                                  const float* __restrict__ bias,
                                                  float* __restrict__ C,
                                                  float* __restrict__ Cp,
                                                  int M, int N, int K) {
    __shared__ __attribute__((aligned(16))) u16 Ash[128 * 64];
    __shared__ __attribute__((aligned(16))) u16 Bsh[128 * 64];
    int tid = threadIdx.x;
    int m0 = blockIdx.y * 128, n0 = blockIdx.x * 128;
    int klen = K / gridDim.z;
    int kbeg = blockIdx.z * klen, kend = kbeg + klen;
    int wave = tid >> 6, lane = tid & 63;
    int l16 = lane & 15, quad = lane >> 4;
    int wr = wave >> 1, wc = wave & 1;
    int lrow = lane >> 3, lcol = lane & 7;      // staging: 8 rows x 8 chunks(16B)
    int scol = lcol ^ lrow;                     // pre-swizzled source chunk
    int sw = l16 & 7;                           // read-side swizzle key (= row&7)

    f32x4 acc[4][4];
    f32x4 zero4 = {0.f, 0.f, 0.f, 0.f};
#pragma unroll
    for (int i = 0; i < 4; ++i)
#pragma unroll
        for (int j = 0; j < 4; ++j) acc[i][j] = zero4;

    for (int kk = kbeg; kk < kend; kk += 64) {
        __syncthreads();                         // WAR: prior ds_reads done
#pragma unroll
        for (int j = 0; j < 4; ++j) {
            int rbase = wave * 32 + j * 8;       // wave-uniform, 8-aligned
            size_t ga = (size_t)(m0 + rbase + lrow) * K + kk + scol * 8;
            size_t gb = (size_t)(n0 + rbase + lrow) * K + kk + scol * 8;
            GLL16(A + ga, &Ash[rbase * 64]);
            GLL16(B + gb, &Bsh[rbase * 64]);
        }
        __syncthreads();                         // vmcnt(0) drain -> data visible
#pragma unroll
        for (int kc = 0; kc < 2; ++kc) {
            f16x8 af[4], bv[4];
#pragma unroll
            for (int i = 0; i < 4; ++i)
                af[i] = *(const f16x8*)&Ash[(wr * 64 + i * 16 + l16) * 64
                                            + (((kc * 4 + quad) ^ sw) << 3)];
#pragma unroll
            for (int j = 0; j < 4; ++j)
                bv[j] = *(const f16x8*)&Bsh[(wc * 64 + j * 16 + l16) * 64
                                            + (((kc * 4 + quad) ^ sw) << 3)];
#pragma unroll
            for (int i = 0; i < 4; ++i)
#pragma unroll
                for (int j = 0; j < 4; ++j)
                    acc[i][j] = __builtin_amdgcn_mfma_f32_16x16x32_f16(af[i], bv[j], acc[i][j], 0, 0, 0);
        }
    }
    float* dst = (blockIdx.z == 0) ? C : Cp;
    bool addb = (bias != nullptr) && (blockIdx.z == 0);
#pragma unroll
    for (int i = 0; i < 4; ++i)
#pragma unroll
        for (int r = 0; r < 4; ++r) {
            int row = m0 + wr * 64 + i * 16 + quad * 4 + r;
#pragma unroll
            for (int j = 0; j < 4; ++j) {
                int col = n0 + wc * 64 + j * 16 + l16;
                float v = acc[i][j][r];
                if (addb) v += bias[col];
                dst[(size_t)row * N + col] = v;
            }
        }
}

// ---- out += partial (fp32, float4) ----
__global__ void k_reduce(float* __restrict__ out, const float* __restrict__ part, int n4) {
    int i = blockIdx.x * 256 + threadIdx.x;
    if (i >= n4) return;
    float4 a = ((const float4*)out)[i];
    float4 b = ((const float4*)part)[i];
    a.x += b.x; a.y += b.y; a.z += b.z; a.w += b.w;
    ((float4*)out)[i] = a;
}

// ---- RoPE (fp64 angles) -> Qh/Ql (S,3584), Kh (S,512) fp16 ----
// Pair restructure (R8): each thread rotates the (d, d+64) PAIR, loading each
// Y/Yp element exactly once (was twice) -> halves the 134MB read traffic.
// Q pre-scaled by 1/sqrt(HD)*log2(e): scores exit QK^T in log2 domain.
__global__ void k_rope2(const float* __restrict__ Y, const float* __restrict__ Yp,
                        const int* __restrict__ pos,
                        u16* __restrict__ Qh, u16* __restrict__ Ql,
                        u16* __restrict__ Kh) {
    __shared__ double finv[64];
    int tid = threadIdx.x;
    if (tid < 64)   // inv_freq = theta^(-i/64) = 2^(-i*log2(1e6)/64)
        finv[tid] = exp2(-0.3114307588956902 * (double)tid);
    __syncthreads();
    int s = blockIdx.x;
    double p = (double)pos[s];
    const float* y  = Y + (size_t)s * NQKV;
    const float* yp = Yp ? (Yp + (size_t)s * NQKV) : nullptr;
    const float QSCALE = 0.1275174313f;     // (1/sqrt(128)) * log2(e)
    for (int u = tid; u < 2048; u += 256) {
        int blk = u >> 6, i = u & 63;        // 128-wide head-half block, freq idx
        int idx  = blk * 128 + i;            // d = i (< 64)
        int idx2 = idx + 64;                 // d = i + 64 (same head block)
        double ang = p * finv[i];
        double n = rint(ang * 0.15915494309189535);          // /(2*pi)
        float r = (float)fma(-6.283185307179586, n, ang);    // range-reduced angle
        float sn, cs;
        __sincosf(r, &sn, &cs);
        float v1 = y[idx], v2 = y[idx2];
        if (yp) { v1 += yp[idx]; v2 += yp[idx2]; }
        float o1 = v1 * cs - v2 * sn;
        float o2 = v2 * cs + v1 * sn;
        if (idx < 3584) {
            u16 hh, ll;
            split2(o1 * QSCALE, hh, ll);
            Qh[(size_t)s * 3584 + idx] = hh;
            Ql[(size_t)s * 3584 + idx] = ll;
            split2(o2 * QSCALE, hh, ll);
            Qh[(size_t)s * 3584 + idx2] = hh;
            Ql[(size_t)s * 3584 + idx2] = ll;
        } else {
            Kh[(size_t)s * 512 + (idx  - 3584)] = f2h(o1);
            Kh[(size_t)s * 512 + (idx2 - 3584)] = f2h(o2);
        }
    }
}

// ---- transpose V section of Y: (S x 512) fp32 -> Vt (512 x S) fp16 ----
__global__ __launch_bounds__(256) void k_vtrans(const float* __restrict__ Y,
                                                const float* __restrict__ Yp,
                                                u16* __restrict__ Vt) {
    __shared__ __attribute__((aligned(16))) u16 T[64][72];
    int s0 = blockIdx.x * 64, d0 = blockIdx.y * 64;
    int tid = threadIdx.x;
#pragma unroll
    for (int t = 0; t < 16; ++t) {
        int idx = tid + t * 256;
        int r = idx >> 6, c = idx & 63;
        size_t goff = (size_t)(s0 + r) * NQKV + 4096 + d0 + c;
        float val = Y[goff];
        if (Yp) val += Yp[goff];
        T[c][r] = f2h(val);
    }
    __syncthreads();
#pragma unroll
    for (int t = 0; t < 2; ++t) {
        int cc = tid + t * 256;
        int dr = cc >> 3, s8 = (cc & 7) << 3;
        *(u16x8*)(Vt + (size_t)(d0 + dr) * Sq + s0 + s8) = *(const u16x8*)&T[dr][s8];
    }
}

// ---- flash attention fp16: persistent blocks, LPT queue, NO K/V staging ----
// R8 (Common-mistake #7): one kt tile of K+V = 32KB (L1-sized, L2/L3-resident;
// K+V per kvh head = 1MB total). LDS staging bought nothing and cost:
// 2 __syncthreads per kt (4-wave lockstep), 8 prefetch VGPRs, and a 40KB LDS
// footprint capping occupancy at 3 blocks/CU. Now MFMA B-fragments are read
// directly from global (per-fragment: 16 rows x 64B segments = same 16
// transactions the staging made); the 4 waves of a block share the tile via
// L1. LDS = wave-private Ps only (8.2KB); barriers only at the item queue.
// Softmax in log2 domain + T13 defer-max + T5 setprio.
// R3 lesson: no min-waves clamp. R5 lesson: no device fences in the loop.
__global__ __launch_bounds__(256) void k_attn(const u16* __restrict__ Qh,
                                              const u16* __restrict__ Ql,
                                              const u16* __restrict__ Kh,
                                              const u16* __restrict__ Vt,
                                              u16* __restrict__ AO,
                                              int* __restrict__ ctr) {
    __shared__ __attribute__((aligned(16))) u16 Ps[4][16][64]; // 8192 B, swizzled
    __shared__ int s_item;

    int tid = threadIdx.x;
    int wave = tid >> 6, lane = tid & 63, l16 = lane & 15, quad = lane >> 4;
    int sw = l16 & 7;                       // Ps swizzle key (= row&7)

    for (;;) {
        __syncthreads();                   // all waves done with prior item
        if (tid == 0) s_item = atomicAdd(ctr, 1);
        __syncthreads();
        int item = s_item;
        if (item >= 32 * NH) break;        // block-uniform exit
        int qt = 31 - item / NH;           // longest first (LPT)
        int h  = item % NH;
        int q0 = qt * 64;
        int kvh = h / 7;                   // NH/NKV = 7

        const u16* Kbase = Kh + kvh * HD;                  // row stride 512
        const u16* Vbase = Vt + (size_t)(kvh * HD) * Sq;   // row stride Sq

        // Q fragments hi/lo direct from global (A-layout: m=l16, k=quad*8+j)
        f16x8 qfh[4], qfl[4];
        {
            size_t qoff = (size_t)(q0 + wave * 16 + l16) * Hdim + h * HD + quad * 8;
#pragma unroll
            for (int kc = 0; kc < 4; ++kc) {
                qfh[kc] = *(const f16x8*)(Qh + qoff + kc * 32);
                qfl[kc] = *(const f16x8*)(Ql + qoff + kc * 32);
            }
        }

        f32x4 O[8];
        f32x4 zero4 = {0.f, 0.f, 0.f, 0.f};
#pragma unroll
        for (int t = 0; t < 8; ++t) O[t] = zero4;
        float mrow[4], lrow[4];
#pragma unroll
        for (int r = 0; r < 4; ++r) { mrow[r] = -1e30f; lrow[r] = 0.f; }

        for (int kt = 0; kt <= qt; ++kt) {
            int k0 = kt * 64;

            // ---- QK^T: B-fragments direct from global (L1/L2-resident) ----
            f32x4 sa[4];                       // S = Q K^T, 2-term split
            __builtin_amdgcn_s_setprio(1);
#pragma unroll
            for (int ct = 0; ct < 4; ++ct) {
                const u16* kr = Kbase + (size_t)(k0 + ct * 16 + l16) * 512 + quad * 8;
                f32x4 z = zero4;
#pragma unroll
                for (int kc = 0; kc < 4; ++kc) {
                    f16x8 b = *(const f16x8*)(kr + kc * 32);
                    z = __builtin_amdgcn_mfma_f32_16x16x32_f16(qfh[kc], b, z, 0, 0, 0);
                    z = __builtin_amdgcn_mfma_f32_16x16x32_f16(qfl[kc], b, z, 0, 0, 0);
                }
                sa[ct] = z;
            }
            __builtin_amdgcn_s_setprio(0);
            if (kt == qt) {
#pragma unroll
                for (int ct = 0; ct < 4; ++ct)
#pragma unroll
                    for (int r = 0; r < 4; ++r)
                        if (k0 + ct * 16 + l16 > q0 + wave * 16 + quad * 4 + r) sa[ct][r] = -1e30f;
            }
            // row max of this tile
            float pmax[4];
#pragma unroll
            for (int r = 0; r < 4; ++r) {
                float mx = fmaxf(fmaxf(sa[0][r], sa[1][r]), fmaxf(sa[2][r], sa[3][r]));
#pragma unroll
                for (int off = 1; off < 16; off <<= 1)
                    mx = fmaxf(mx, __shfl_xor(mx, off, 64));
                pmax[r] = mx;
            }
            // T13 defer-max: skip rescale while max growth <= 8 (P <= 2^8)
            bool keep = (pmax[0] <= mrow[0] + 8.f) && (pmax[1] <= mrow[1] + 8.f) &&
                        (pmax[2] <= mrow[2] + 8.f) && (pmax[3] <= mrow[3] + 8.f);
            if (!__all(keep)) {
#pragma unroll
                for (int r = 0; r < 4; ++r) {
                    float mnew = fmaxf(mrow[r], pmax[r]);
                    float alpha = exp2f(mrow[r] - mnew);
                    mrow[r] = mnew;
                    lrow[r] *= alpha;
#pragma unroll
                    for (int ct = 0; ct < 8; ++ct) O[ct][r] *= alpha;
                }
            }
            float rs[4] = {0.f, 0.f, 0.f, 0.f};
#pragma unroll
            for (int ct = 0; ct < 4; ++ct)
#pragma unroll
                for (int r = 0; r < 4; ++r) {
                    float p = exp2f(sa[ct][r] - mrow[r]);
                    rs[r] += p;
                    // swizzled Ps write: chunk ^= row&7, row = quad*4+r
                    Ps[wave][quad * 4 + r][(ct * 16 + l16) ^ (((quad * 4 + r) & 7) << 3)] = f2h(p);
                }
#pragma unroll
            for (int r = 0; r < 4; ++r) {
#pragma unroll
                for (int off = 1; off < 16; off <<= 1)
                    rs[r] += __shfl_xor(rs[r], off, 64);
                lrow[r] += rs[r];
            }
            // ---- PV: V-fragments direct from global (Ps wave-private) ----
            __builtin_amdgcn_s_setprio(1);
#pragma unroll
            for (int kc = 0; kc < 2; ++kc) {
                f16x8 a = *(const f16x8*)&Ps[wave][l16][(((kc * 4 + quad) ^ sw)) << 3];
#pragma unroll
                for (int ct = 0; ct < 8; ++ct) {
                    f16x8 b = *(const f16x8*)(Vbase + (size_t)(ct * 16 + l16) * Sq
                                              + k0 + kc * 32 + quad * 8);
                    O[ct] = __builtin_amdgcn_mfma_f32_16x16x32_f16(a, b, O[ct], 0, 0, 0);
                }
            }
            __builtin_amdgcn_s_setprio(0);
        }
#pragma unroll
        for (int r = 0; r < 4; ++r) {
            float inv = 1.f / lrow[r];
            int row = q0 + wave * 16 + quad * 4 + r;
#pragma unroll
            for (int ct = 0; ct < 8; ++ct)
                AO[(size_t)row * 3584 + h * HD + ct * 16 + l16] = f2h(O[ct][r] * inv);
        }
    }
}

extern "C" void kernel_launch(void* const* d_in, const int* in_sizes, int n_in,
                              void* d_out, int out_size, void* d_ws, size_t ws_size,
                              hipStream_t stream) {
    (void)in_sizes; (void)n_in; (void)out_size;
    const float* hidden = (const float*)d_in[0];
    const int*   pos    = (const int*)d_in[1];
    const int*   qw_q = (const int*)d_in[2];
    const int*   qz_q = (const int*)d_in[3];
    const float* sc_q = (const float*)d_in[4];
    const float* b_q  = (const float*)d_in[5];
    const int*   qw_k = (const int*)d_in[6];
    const int*   qz_k = (const int*)d_in[7];
    const float* sc_k = (const float*)d_in[8];
    const float* b_k  = (const float*)d_in[9];
    const int*   qw_v = (const int*)d_in[10];
    const int*   qz_v = (const int*)d_in[11];
    const float* sc_v = (const float*)d_in[12];
    const float* b_v  = (const float*)d_in[13];
    const int*   qw_o = (const int*)d_in[14];
    const int*   qz_o = (const int*)d_in[15];
    const float* sc_o = (const float*)d_in[16];
    float* out = (float*)d_out;

    char* base = (char*)d_ws;
    size_t off = 0;
    auto alloc = [&](size_t bytes) {
        char* p = base + off;
        off += (bytes + 255) & ~(size_t)255;
        return p;
    };
    u16* Wh = (u16*)alloc((size_t)NQKV * KD * 2);   // 33.0 MB (reused for W_o)
    u16* Xh = (u16*)alloc((size_t)Sq * Hdim * 2);   // 14.7 MB (reused as Qh, then partial)
    u16* Xl = (u16*)alloc((size_t)Sq * Hdim * 2);   // 14.7 MB (Ql, then partial)
    float* Y = (float*)alloc((size_t)Sq * NQKV * 4);// 37.7 MB (reused for AO)
    u16* Khb = (u16*)alloc((size_t)Sq * 512 * 2);   //  2.1 MB
    u16* Vt  = (u16*)alloc((size_t)512 * Sq * 2);   //  2.1 MB
    float* biasc = (float*)alloc(NQKV * 4);
    int*   ctr   = (int*)alloc(4096);               // attn work-queue counter
    // split-K partial for GEMM1 (live GEMM1 -> rope/vtrans); gated on ws_size
    float* Part1 = (float*)alloc((size_t)Sq * NQKV * 4);   // 37.7 MB
    bool deep = (off <= ws_size);
    u16* Qhb = Xh;                 // Xh dead after GEMM1
    u16* Qlb = Xl;
    u16* AO  = (u16*)Y;            // Y dead after rope/vtrans
    u16* Wo  = Wh;                 // Wh dead after GEMM1
    float* Part = (float*)Xh;      // Xh+Xl contiguous = 29.4 MB, dead after attn

    hipMemsetAsync(ctr, 0, 4096, stream);           // ws is re-poisoned each call
    k_cvt<<<3584, 256, 0, stream>>>(hidden, Xh, (Sq * Hdim) / 8);
    k_bias<<<18, 256, 0, stream>>>(b_q, b_k, b_v, biasc);
    k_dequant<<<dim3(3584 / 64, KD / 64), 256, 0, stream>>>(qw_q, qz_q, sc_q, Wh, 3584);
    k_dequant<<<dim3(512 / 64, KD / 64), 256, 0, stream>>>(qw_k, qz_k, sc_k, Wh + (size_t)3584 * KD, 512);
    k_dequant<<<dim3(512 / 64, KD / 64), 256, 0, stream>>>(qw_v, qz_v, sc_v, Wh + (size_t)4096 * KD, 512);
    // GEMM1: split-K=2 -> 1152 blocks = 4.5/CU; partial folded into rope/vtrans.
    if (deep) {
        k_gemm_f16<<<dim3(NQKV / 128, Sq / 128, 2), 256, 0, stream>>>(Xh, Wh, biasc, Y, Part1, Sq, NQKV, KD);
    } else {
        k_gemm_f16<<<dim3(NQKV / 128, Sq / 128, 1), 256, 0, stream>>>(Xh, Wh, biasc, Y, nullptr, Sq, NQKV, KD);
    }
    k_rope2<<<Sq, 256, 0, stream>>>(Y, deep ? Part1 : nullptr, pos, Qhb, Qlb, Khb);
    k_vtrans<<<dim3(Sq / 64, 512 / 64), 256, 0, stream>>>(Y, deep ? Part1 : nullptr, Vt);
    k_dequant<<<dim3(3584 / 64, KD / 64), 256, 0, stream>>>(qw_o, qz_o, sc_o, Wo, 3584);
    k_attn<<<dim3(1024), 256, 0, stream>>>(Qhb, Qlb, Khb, Vt, AO, ctr);
    k_gemm_f16<<<dim3(Hdim / 128, Sq / 128, 2), 256, 0, stream>>>(AO, Wo, nullptr, out, Part, Sq, Hdim, KD);
    k_reduce<<<(Sq * Hdim / 4 + 255) / 256, 256, 0, stream>>>(out, Part, Sq * Hdim / 4);
}

// Round 9
// 521.099 us; speedup vs baseline: 1.2330x; 1.2330x over previous
//
#include <hip/hip_runtime.h>

// ---- problem constants ----
#define Hdim   3584
#define NH     28
#define NKV    4
#define HD     128
#define Sq     2048
#define NQKV   4608          // 3584 q + 512 k + 512 v
#define KD     3584          // inner dim of both GEMMs

typedef unsigned short u16;
typedef unsigned int   u32;
typedef _Float16 f16;
typedef _Float16 f16x8 __attribute__((ext_vector_type(8)));     // MFMA A/B operand (4 VGPRs)
typedef unsigned short u16x8 __attribute__((ext_vector_type(8)));
typedef float f32x4 __attribute__((ext_vector_type(4)));        // MFMA C/D operand

__device__ __forceinline__ u16 f2h(float x) { f16 h = (f16)x; return __builtin_bit_cast(u16, h); }
__device__ __forceinline__ float h2f(u16 b) { return (float)__builtin_bit_cast(f16, b); }
__device__ __forceinline__ void split2(float x, u16& hi, u16& lo) {
    hi = f2h(x);
    lo = f2h(x - h2f(hi));   // combined ~22-bit mantissa
}

// async global->LDS, 16B per lane; LDS dest = wave-uniform base + lane*16
#define GLL16(gp, lp) __builtin_amdgcn_global_load_lds( \
    (__attribute__((address_space(1))) void*)(gp),      \
    (__attribute__((address_space(3))) void*)(lp), 16, 0, 0)

// ---- fp32 -> fp16, 8 elems/thread ----
__global__ void k_cvt(const float* __restrict__ x, u16* __restrict__ yh, int n8) {
    int i = blockIdx.x * 256 + threadIdx.x;
    if (i >= n8) return;
    const float4* p = (const float4*)(x + (size_t)i * 8);
    float4 a = p[0], b = p[1];
    float v[8] = {a.x, a.y, a.z, a.w, b.x, b.y, b.z, b.w};
    u16x8 h;
#pragma unroll
    for (int j = 0; j < 8; ++j) h[j] = f2h(v[j]);
    *(u16x8*)(yh + (size_t)i * 8) = h;
}

// ---- concat biases (q|k|v) ----
__global__ void k_bias(const float* __restrict__ bq, const float* __restrict__ bk,
                       const float* __restrict__ bv, float* __restrict__ out) {
    int i = blockIdx.x * 256 + threadIdx.x;
    if (i >= NQKV) return;
    out[i] = (i < 3584) ? bq[i] : (i < 4096 ? bk[i - 3584] : bv[i - 4096]);
}

// ---- AWQ int4 dequant -> W (dout x KD) fp16 --- tiled LDS transpose ----
// R7: coalesced qw staging into LDS removed the stride-1792B gather that was
// hiding ~100us below the top-5 cutoff.
__global__ __launch_bounds__(256) void k_dequant(const int* __restrict__ qw,
                                                 const int* __restrict__ qz,
                                                 const float* __restrict__ sc,
                                                 u16* __restrict__ W, int dout) {
    __shared__ u32 L[64][9];       // 64 rows x 8 words (+1 pad: breaks bank resonance)
    __shared__ float scl[64];
    __shared__ u32 zq[8];
    int tid = threadIdx.x;
    int w8 = dout >> 3;
    int c0 = blockIdx.x * 64, j0 = blockIdx.x * 8;
    int r0 = blockIdx.y * 64, g = r0 >> 7;       // G=128, r0%128 in {0,64} -> uniform
#pragma unroll
    for (int t = 0; t < 2; ++t) {
        int u = tid + t * 256;
        int rr = u >> 3, jj = u & 7;             // coalesced: 8 consecutive words/row
        L[rr][jj] = (u32)qw[(size_t)(r0 + rr) * w8 + j0 + jj];
    }
    if (tid < 64) scl[tid] = sc[(size_t)g * dout + c0 + tid];
    if (tid < 8)  zq[tid]  = (u32)qz[(size_t)g * w8 + j0 + tid];
    __syncthreads();
#pragma unroll
    for (int t = 0; t < 2; ++t) {
        int u = tid + t * 256;
        int lc = u >> 3, r8 = (u & 7) << 3;      // chunk: col c0+lc, rows r0+r8..+7
        int sh = (lc & 7) << 2, jc = lc >> 3;
        int z = (int)((zq[jc] >> sh) & 15u);
        float s = scl[lc];
        u16x8 v;
#pragma unroll
        for (int i = 0; i < 8; ++i) {
            int w = (int)((L[r8 + i][jc] >> sh) & 15u);
            v[i] = f2h((float)(w - z) * s);
        }
        *(u16x8*)(W + (size_t)(c0 + lc) * KD + r0 + r8) = v;
    }
}

// ---- fp16 MFMA GEMM (m97-style + T2 XOR-swizzle): C = A @ B^T + bias ----
// T2: 128B LDS row stride = 32 banks -> chunk16B ^= row&7 on BOTH sides.
// Measured R4: SQ_LDS_BANK_CONFLICT = 0.
// R6 lesson: XCD-chunked blockIdx remap INCREASED FETCH 124->183MB; linear
// order already time-shares one A-panel across XCDs via L3. Keep linear.
__global__ __launch_bounds__(256) void k_gemm_f16(const u16* __restrict__ A,
                                                  const u16* __restrict__ B,
                                                  const float* __restrict__ bias,
                                                  float* __restrict__ C,
                                                  float* __restrict__ Cp,
                                                  int M, int N, int K) {
    __shared__ __attribute__((aligned(16))) u16 Ash[128 * 64];
    __shared__ __attribute__((aligned(16))) u16 Bsh[128 * 64];
    int tid = threadIdx.x;
    int m0 = blockIdx.y * 128, n0 = blockIdx.x * 128;
    int klen = K / gridDim.z;
    int kbeg = blockIdx.z * klen, kend = kbeg + klen;
    int wave = tid >> 6, lane = tid & 63;
    int l16 = lane & 15, quad = lane >> 4;
    int wr = wave >> 1, wc = wave & 1;
    int lrow = lane >> 3, lcol = lane & 7;      // staging: 8 rows x 8 chunks(16B)
    int scol = lcol ^ lrow;                     // pre-swizzled source chunk
    int sw = l16 & 7;                           // read-side swizzle key (= row&7)

    f32x4 acc[4][4];
    f32x4 zero4 = {0.f, 0.f, 0.f, 0.f};
#pragma unroll
    for (int i = 0; i < 4; ++i)
#pragma unroll
        for (int j = 0; j < 4; ++j) acc[i][j] = zero4;

    for (int kk = kbeg; kk < kend; kk += 64) {
        __syncthreads();                         // WAR: prior ds_reads done
#pragma unroll
        for (int j = 0; j < 4; ++j) {
            int rbase = wave * 32 + j * 8;       // wave-uniform, 8-aligned
            size_t ga = (size_t)(m0 + rbase + lrow) * K + kk + scol * 8;
            size_t gb = (size_t)(n0 + rbase + lrow) * K + kk + scol * 8;
            GLL16(A + ga, &Ash[rbase * 64]);
            GLL16(B + gb, &Bsh[rbase * 64]);
        }
        __syncthreads();                         // vmcnt(0) drain -> data visible
#pragma unroll
        for (int kc = 0; kc < 2; ++kc) {
            f16x8 af[4], bv[4];
#pragma unroll
            for (int i = 0; i < 4; ++i)
                af[i] = *(const f16x8*)&Ash[(wr * 64 + i * 16 + l16) * 64
                                            + (((kc * 4 + quad) ^ sw) << 3)];
#pragma unroll
            for (int j = 0; j < 4; ++j)
                bv[j] = *(const f16x8*)&Bsh[(wc * 64 + j * 16 + l16) * 64
                                            + (((kc * 4 + quad) ^ sw) << 3)];
#pragma unroll
            for (int i = 0; i < 4; ++i)
#pragma unroll
                for (int j = 0; j < 4; ++j)
                    acc[i][j] = __builtin_amdgcn_mfma_f32_16x16x32_f16(af[i], bv[j], acc[i][j], 0, 0, 0);
        }
    }
    float* dst = (blockIdx.z == 0) ? C : Cp;
    bool addb = (bias != nullptr) && (blockIdx.z == 0);
#pragma unroll
    for (int i = 0; i < 4; ++i)
#pragma unroll
        for (int r = 0; r < 4; ++r) {
            int row = m0 + wr * 64 + i * 16 + quad * 4 + r;
#pragma unroll
            for (int j = 0; j < 4; ++j) {
                int col = n0 + wc * 64 + j * 16 + l16;
                float v = acc[i][j][r];
                if (addb) v += bias[col];
                dst[(size_t)row * N + col] = v;
            }
        }
}

// ---- out += partial (fp32, float4) ----
__global__ void k_reduce(float* __restrict__ out, const float* __restrict__ part, int n4) {
    int i = blockIdx.x * 256 + threadIdx.x;
    if (i >= n4) return;
    float4 a = ((const float4*)out)[i];
    float4 b = ((const float4*)part)[i];
    a.x += b.x; a.y += b.y; a.z += b.z; a.w += b.w;
    ((float4*)out)[i] = a;
}

// ---- RoPE (fp64 angles) -> Qh/Ql (S,3584), Kh (S,512) fp16 ----
// Pair restructure: each thread rotates the (d, d+64) PAIR, loading each
// Y/Yp element exactly once. Q pre-scaled by 1/sqrt(HD)*log2(e).
__global__ void k_rope2(const float* __restrict__ Y, const float* __restrict__ Yp,
                        const int* __restrict__ pos,
                        u16* __restrict__ Qh, u16* __restrict__ Ql,
                        u16* __restrict__ Kh) {
    __shared__ double finv[64];
    int tid = threadIdx.x;
    if (tid < 64)   // inv_freq = theta^(-i/64) = 2^(-i*log2(1e6)/64)
        finv[tid] = exp2(-0.3114307588956902 * (double)tid);
    __syncthreads();
    int s = blockIdx.x;
    double p = (double)pos[s];
    const float* y  = Y + (size_t)s * NQKV;
    const float* yp = Yp ? (Yp + (size_t)s * NQKV) : nullptr;
    const float QSCALE = 0.1275174313f;     // (1/sqrt(128)) * log2(e)
    for (int u = tid; u < 2048; u += 256) {
        int blk = u >> 6, i = u & 63;        // 128-wide head-half block, freq idx
        int idx  = blk * 128 + i;            // d = i (< 64)
        int idx2 = idx + 64;                 // d = i + 64 (same head block)
        double ang = p * finv[i];
        double n = rint(ang * 0.15915494309189535);          // /(2*pi)
        float r = (float)fma(-6.283185307179586, n, ang);    // range-reduced angle
        float sn, cs;
        __sincosf(r, &sn, &cs);
        float v1 = y[idx], v2 = y[idx2];
        if (yp) { v1 += yp[idx]; v2 += yp[idx2]; }
        float o1 = v1 * cs - v2 * sn;
        float o2 = v2 * cs + v1 * sn;
        if (idx < 3584) {
            u16 hh, ll;
            split2(o1 * QSCALE, hh, ll);
            Qh[(size_t)s * 3584 + idx] = hh;
            Ql[(size_t)s * 3584 + idx] = ll;
            split2(o2 * QSCALE, hh, ll);
            Qh[(size_t)s * 3584 + idx2] = hh;
            Ql[(size_t)s * 3584 + idx2] = ll;
        } else {
            Kh[(size_t)s * 512 + (idx  - 3584)] = f2h(o1);
            Kh[(size_t)s * 512 + (idx2 - 3584)] = f2h(o2);
        }
    }
}

// ---- transpose V section of Y: (S x 512) fp32 -> Vt (512 x S) fp16 ----
__global__ __launch_bounds__(256) void k_vtrans(const float* __restrict__ Y,
                                                const float* __restrict__ Yp,
                                                u16* __restrict__ Vt) {
    __shared__ __attribute__((aligned(16))) u16 T[64][72];
    int s0 = blockIdx.x * 64, d0 = blockIdx.y * 64;
    int tid = threadIdx.x;
#pragma unroll
    for (int t = 0; t < 16; ++t) {
        int idx = tid + t * 256;
        int r = idx >> 6, c = idx & 63;
        size_t goff = (size_t)(s0 + r) * NQKV + 4096 + d0 + c;
        float val = Y[goff];
        if (Yp) val += Yp[goff];
        T[c][r] = f2h(val);
    }
    __syncthreads();
#pragma unroll
    for (int t = 0; t < 2; ++t) {
        int cc = tid + t * 256;
        int dr = cc >> 3, s8 = (cc & 7) << 3;
        *(u16x8*)(Vt + (size_t)(d0 + dr) * Sq + s0 + s8) = *(const u16x8*)&T[dr][s8];
    }
}

// ---- flash attention fp16: persistent blocks, LPT queue, reg-prefetch ----
// R8 lesson: K/V LDS staging is SOFTWARE PREFETCH, not bandwidth management.
// Direct-from-global B-fragments put 32 dependent VMEM loads on the MFMA
// critical path (attn 121->299us, all pipes idle). Staging stays.
// R9 VALU diet (VALUBusy was 36% vs MfmaUtil 15.8%):
//  (1) defer-max check uses LANE-LOCAL max (provably == row-max check under
//      __all); wave shuffle-max only inside the rare rescale branch.
//  (2) row-sum via ones-MFMA: O[8] accumulates mfma(P,1) -> lrow == O[8][r];
//      deletes 16 shuffle-adds + 16 adds/tile, runs on the idle MFMA pipe.
// LDS: XOR-swizzled power-of-2 tiles (chunk16B ^= row&7), 40960 B total.
// Softmax in log2 domain + T13 defer-max + T5 setprio.
// R3 lesson: no min-waves clamp. R5 lesson: no device fences in the loop.
__global__ __launch_bounds__(256) void k_attn(const u16* __restrict__ Qh,
                                              const u16* __restrict__ Ql,
                                              const u16* __restrict__ Kh,
                                              const u16* __restrict__ Vt,
                                              u16* __restrict__ AO,
                                              int* __restrict__ ctr) {
    __shared__ __attribute__((aligned(16))) u16 Ks[64][128];   // 16384 B, swizzled
    __shared__ __attribute__((aligned(16))) u16 Vs[128][64];   // 16384 B, swizzled
    __shared__ __attribute__((aligned(16))) u16 Ps[4][16][64]; //  8192 B, swizzled

    int tid = threadIdx.x;
    int wave = tid >> 6, lane = tid & 63, l16 = lane & 15, quad = lane >> 4;
    int sw = l16 & 7;                       // read-side swizzle key (= row&7)
    f16x8 onesf;
#pragma unroll
    for (int j = 0; j < 8; ++j) onesf[j] = (f16)1.f;

    for (;;) {
        __syncthreads();                   // all waves done with prior item
        if (tid == 0) *(int*)&Ks[0][0] = atomicAdd(ctr, 1);
        __syncthreads();
        int item = *(const int*)&Ks[0][0];
        if (item >= 32 * NH) break;        // block-uniform exit
        int qt = 31 - item / NH;           // longest first (LPT)
        int h  = item % NH;
        int q0 = qt * 64;
        int kvh = h / 7;                   // NH/NKV = 7
        __syncthreads();                   // item slot read by all before staging

        const u16* Kbase = Kh + kvh * HD;                  // row stride 512
        const u16* Vbase = Vt + (size_t)(kvh * HD) * Sq;   // row stride Sq

        // Q fragments hi/lo direct from global (A-layout: m=l16, k=quad*8+j)
        f16x8 qfh[4], qfl[4];
        {
            size_t qoff = (size_t)(q0 + wave * 16 + l16) * Hdim + h * HD + quad * 8;
#pragma unroll
            for (int kc = 0; kc < 4; ++kc) {
                qfh[kc] = *(const f16x8*)(Qh + qoff + kc * 32);
                qfl[kc] = *(const f16x8*)(Ql + qoff + kc * 32);
            }
        }

        // initial staging of tile 0 (swizzled writes)
#pragma unroll
        for (int t = 0; t < 4; ++t) {
            int c = tid + t * 256;
            int row = c >> 4, ch = (c & 15) ^ (row & 7);
            *(u16x8*)&Ks[row][ch << 3] = *(const u16x8*)(Kbase + (size_t)row * 512 + ((c & 15) << 3));
        }
#pragma unroll
        for (int t = 0; t < 4; ++t) {
            int c = tid + t * 256;
            int d = c >> 3, ch = (c & 7) ^ (d & 7);
            *(u16x8*)&Vs[d][ch << 3] = *(const u16x8*)(Vbase + (size_t)d * Sq + ((c & 7) << 3));
        }
        __syncthreads();

        f32x4 O[9];                        // O[0..7] = output d-tiles, O[8] = row-sum
        f32x4 zero4 = {0.f, 0.f, 0.f, 0.f};
#pragma unroll
        for (int t = 0; t < 9; ++t) O[t] = zero4;
        float mrow[4];
#pragma unroll
        for (int r = 0; r < 4; ++r) mrow[r] = -1e30f;

        for (int kt = 0; kt <= qt; ++kt) {
            int k0 = kt * 64;
            int kn = (kt < qt) ? k0 + 64 : k0;     // clamped prefetch base

            // ---- issue next-tile loads into registers (latency overlapped) ----
            u16x8 nk[4], nv[4];
#pragma unroll
            for (int t = 0; t < 4; ++t) {
                int c = tid + t * 256;
                nk[t] = *(const u16x8*)(Kbase + (size_t)(kn + (c >> 4)) * 512 + ((c & 15) << 3));
                nv[t] = *(const u16x8*)(Vbase + (size_t)(c >> 3) * Sq + kn + ((c & 7) << 3));
            }

            // ---- compute current tile from LDS (log2-domain scores) ----
            f32x4 sa[4];                       // S = Q K^T, 2-term split
            __builtin_amdgcn_s_setprio(1);
#pragma unroll
            for (int ct = 0; ct < 4; ++ct) {
                f32x4 z = zero4;
#pragma unroll
                for (int kc = 0; kc < 4; ++kc) {
                    f16x8 b = *(const f16x8*)&Ks[ct * 16 + l16][(((kc * 4 + quad) ^ sw)) << 3];
                    z = __builtin_amdgcn_mfma_f32_16x16x32_f16(qfh[kc], b, z, 0, 0, 0);
                    z = __builtin_amdgcn_mfma_f32_16x16x32_f16(qfl[kc], b, z, 0, 0, 0);
                }
                sa[ct] = z;
            }
            __builtin_amdgcn_s_setprio(0);
            if (kt == qt) {
#pragma unroll
                for (int ct = 0; ct < 4; ++ct)
#pragma unroll
                    for (int r = 0; r < 4; ++r)
                        if (k0 + ct * 16 + l16 > q0 + wave * 16 + quad * 4 + r) sa[ct][r] = -1e30f;
            }
            // lane-local per-row max over this lane's 4 ct values
            float lmax[4];
#pragma unroll
            for (int r = 0; r < 4; ++r)
                lmax[r] = fmaxf(fmaxf(sa[0][r], sa[1][r]), fmaxf(sa[2][r], sa[3][r]));
            // T13 defer-max: __all over lane-local maxes == row-max check
            bool keep = (lmax[0] <= mrow[0] + 8.f) && (lmax[1] <= mrow[1] + 8.f) &&
                        (lmax[2] <= mrow[2] + 8.f) && (lmax[3] <= mrow[3] + 8.f);
            if (!__all(keep)) {                // rare: true row max + rescale
#pragma unroll
                for (int r = 0; r < 4; ++r) {
                    float mx = lmax[r];
#pragma unroll
                    for (int off = 1; off < 16; off <<= 1)
                        mx = fmaxf(mx, __shfl_xor(mx, off, 64));
                    float mnew = fmaxf(mrow[r], mx);
                    float alpha = exp2f(mrow[r] - mnew);
                    mrow[r] = mnew;
#pragma unroll
                    for (int ct = 0; ct < 9; ++ct) O[ct][r] *= alpha;
                }
            }
#pragma unroll
            for (int ct = 0; ct < 4; ++ct)
#pragma unroll
                for (int r = 0; r < 4; ++r) {
                    float p = exp2f(sa[ct][r] - mrow[r]);
                    // swizzled Ps write: chunk ^= row&7, row = quad*4+r
                    Ps[wave][quad * 4 + r][(ct * 16 + l16) ^ (((quad * 4 + r) & 7) << 3)] = f2h(p);
                }
            // ---- PV + ones-MFMA row-sum (Ps wave-private) ----
            __builtin_amdgcn_s_setprio(1);
#pragma unroll
            for (int kc = 0; kc < 2; ++kc) {
                f16x8 a = *(const f16x8*)&Ps[wave][l16][(((kc * 4 + quad) ^ sw)) << 3];
#pragma unroll
                for (int ct = 0; ct < 8; ++ct) {
                    f16x8 b = *(const f16x8*)&Vs[ct * 16 + l16][(((kc * 4 + quad) ^ sw)) << 3];
                    O[ct] = __builtin_amdgcn_mfma_f32_16x16x32_f16(a, b, O[ct], 0, 0, 0);
                }
                O[8] = __builtin_amdgcn_mfma_f32_16x16x32_f16(a, onesf, O[8], 0, 0, 0);
            }
            __builtin_amdgcn_s_setprio(0);

            // ---- commit prefetched tile to LDS (swizzled) ----
            __syncthreads();                   // all waves done reading Ks/Vs
#pragma unroll
            for (int t = 0; t < 4; ++t) {
                int c = tid + t * 256;
                int row = c >> 4, chk = ((c & 15) ^ (row & 7));
                int d = c >> 3, chv = ((c & 7) ^ (d & 7));
                *(u16x8*)&Ks[row][chk << 3] = nk[t];
                *(u16x8*)&Vs[d][chv << 3]   = nv[t];
            }
            __syncthreads();                   // staged data visible
        }
#pragma unroll
        for (int r = 0; r < 4; ++r) {
            float inv = 1.f / O[8][r];
            int row = q0 + wave * 16 + quad * 4 + r;
#pragma unroll
            for (int ct = 0; ct < 8; ++ct)
                AO[(size_t)row * 3584 + h * HD + ct * 16 + l16] = f2h(O[ct][r] * inv);
        }
    }
}

extern "C" void kernel_launch(void* const* d_in, const int* in_sizes, int n_in,
                              void* d_out, int out_size, void* d_ws, size_t ws_size,
                              hipStream_t stream) {
    (void)in_sizes; (void)n_in; (void)out_size;
    const float* hidden = (const float*)d_in[0];
    const int*   pos    = (const int*)d_in[1];
    const int*   qw_q = (const int*)d_in[2];
    const int*   qz_q = (const int*)d_in[3];
    const float* sc_q = (const float*)d_in[4];
    const float* b_q  = (const float*)d_in[5];
    const int*   qw_k = (const int*)d_in[6];
    const int*   qz_k = (const int*)d_in[7];
    const float* sc_k = (const float*)d_in[8];
    const float* b_k  = (const float*)d_in[9];
    const int*   qw_v = (const int*)d_in[10];
    const int*   qz_v = (const int*)d_in[11];
    const float* sc_v = (const float*)d_in[12];
    const float* b_v  = (const float*)d_in[13];
    const int*   qw_o = (const int*)d_in[14];
    const int*   qz_o = (const int*)d_in[15];
    const float* sc_o = (const float*)d_in[16];
    float* out = (float*)d_out;

    char* base = (char*)d_ws;
    size_t off = 0;
    auto alloc = [&](size_t bytes) {
        char* p = base + off;
        off += (bytes + 255) & ~(size_t)255;
        return p;
    };
    u16* Wh = (u16*)alloc((size_t)NQKV * KD * 2);   // 33.0 MB (reused for W_o)
    u16* Xh = (u16*)alloc((size_t)Sq * Hdim * 2);   // 14.7 MB (reused as Qh, then partial)
    u16* Xl = (u16*)alloc((size_t)Sq * Hdim * 2);   // 14.7 MB (Ql, then partial)
    float* Y = (float*)alloc((size_t)Sq * NQKV * 4);// 37.7 MB (reused for AO)
    u16* Khb = (u16*)alloc((size_t)Sq * 512 * 2);   //  2.1 MB
    u16* Vt  = (u16*)alloc((size_t)512 * Sq * 2);   //  2.1 MB
    float* biasc = (float*)alloc(NQKV * 4);
    int*   ctr   = (int*)alloc(4096);               // attn work-queue counter
    // split-K partial for GEMM1 (live GEMM1 -> rope/vtrans); gated on ws_size
    float* Part1 = (float*)alloc((size_t)Sq * NQKV * 4);   // 37.7 MB
    bool deep = (off <= ws_size);
    u16* Qhb = Xh;                 // Xh dead after GEMM1
    u16* Qlb = Xl;
    u16* AO  = (u16*)Y;            // Y dead after rope/vtrans
    u16* Wo  = Wh;                 // Wh dead after GEMM1
    float* Part = (float*)Xh;      // Xh+Xl contiguous = 29.4 MB, dead after attn

    hipMemsetAsync(ctr, 0, 4096, stream);           // ws is re-poisoned each call
    k_cvt<<<3584, 256, 0, stream>>>(hidden, Xh, (Sq * Hdim) / 8);
    k_bias<<<18, 256, 0, stream>>>(b_q, b_k, b_v, biasc);
    k_dequant<<<dim3(3584 / 64, KD / 64), 256, 0, stream>>>(qw_q, qz_q, sc_q, Wh, 3584);
    k_dequant<<<dim3(512 / 64, KD / 64), 256, 0, stream>>>(qw_k, qz_k, sc_k, Wh + (size_t)3584 * KD, 512);
    k_dequant<<<dim3(512 / 64, KD / 64), 256, 0, stream>>>(qw_v, qz_v, sc_v, Wh + (size_t)4096 * KD, 512);
    // GEMM1: split-K=2 -> 1152 blocks = 4.5/CU; partial folded into rope/vtrans.
    if (deep) {
        k_gemm_f16<<<dim3(NQKV / 128, Sq / 128, 2), 256, 0, stream>>>(Xh, Wh, biasc, Y, Part1, Sq, NQKV, KD);
    } else {
        k_gemm_f16<<<dim3(NQKV / 128, Sq / 128, 1), 256, 0, stream>>>(Xh, Wh, biasc, Y, nullptr, Sq, NQKV, KD);
    }
    k_rope2<<<Sq, 256, 0, stream>>>(Y, deep ? Part1 : nullptr, pos, Qhb, Qlb, Khb);
    k_vtrans<<<dim3(Sq / 64, 512 / 64), 256, 0, stream>>>(Y, deep ? Part1 : nullptr, Vt);
    k_dequant<<<dim3(3584 / 64, KD / 64), 256, 0, stream>>>(qw_o, qz_o, sc_o, Wo, 3584);
    k_attn<<<dim3(1024), 256, 0, stream>>>(Qhb, Qlb, Khb, Vt, AO, ctr);
    k_gemm_f16<<<dim3(Hdim / 128, Sq / 128, 2), 256, 0, stream>>>(AO, Wo, nullptr, out, Part, Sq, Hdim, KD);
    k_reduce<<<(Sq * Hdim / 4 + 255) / 256, 256, 0, stream>>>(out, Part, Sq * Hdim / 4);
}

// Round 10
// 468.543 us; speedup vs baseline: 1.3713x; 1.1122x over previous
//
#include <hip/hip_runtime.h>

// ---- problem constants ----
#define Hdim   3584
#define NH     28
#define NKV    4
#define HD     128
#define Sq     2048
#define NQKV   4608          // 3584 q + 512 k + 512 v
#define KD     3584          // inner dim of both GEMMs

typedef unsigned short u16;
typedef unsigned int   u32;
typedef _Float16 f16;
typedef _Float16 f16x8 __attribute__((ext_vector_type(8)));     // MFMA A/B operand (4 VGPRs)
typedef unsigned short u16x8 __attribute__((ext_vector_type(8)));
typedef float f32x4 __attribute__((ext_vector_type(4)));        // MFMA C/D operand

__device__ __forceinline__ u16 f2h(float x) { f16 h = (f16)x; return __builtin_bit_cast(u16, h); }
__device__ __forceinline__ float h2f(u16 b) { return (float)__builtin_bit_cast(f16, b); }
__device__ __forceinline__ void split2(float x, u16& hi, u16& lo) {
    hi = f2h(x);
    lo = f2h(x - h2f(hi));   // combined ~22-bit mantissa
}

// async global->LDS, 16B per lane; LDS dest = wave-uniform base + lane*16
#define GLL16(gp, lp) __builtin_amdgcn_global_load_lds( \
    (__attribute__((address_space(1))) void*)(gp),      \
    (__attribute__((address_space(3))) void*)(lp), 16, 0, 0)

// ---- fp32 -> fp16, 8 elems/thread ----
__global__ void k_cvt(const float* __restrict__ x, u16* __restrict__ yh, int n8) {
    int i = blockIdx.x * 256 + threadIdx.x;
    if (i >= n8) return;
    const float4* p = (const float4*)(x + (size_t)i * 8);
    float4 a = p[0], b = p[1];
    float v[8] = {a.x, a.y, a.z, a.w, b.x, b.y, b.z, b.w};
    u16x8 h;
#pragma unroll
    for (int j = 0; j < 8; ++j) h[j] = f2h(v[j]);
    *(u16x8*)(yh + (size_t)i * 8) = h;
}

// ---- concat biases (q|k|v) ----
__global__ void k_bias(const float* __restrict__ bq, const float* __restrict__ bk,
                       const float* __restrict__ bv, float* __restrict__ out) {
    int i = blockIdx.x * 256 + threadIdx.x;
    if (i >= NQKV) return;
    out[i] = (i < 3584) ? bq[i] : (i < 4096 ? bk[i - 3584] : bv[i - 4096]);
}

// ---- AWQ int4 dequant -> W (dout x KD) fp16 --- tiled LDS transpose ----
// R7: coalesced qw staging into LDS removed the stride-1792B gather that was
// hiding ~100us below the top-5 cutoff.
__global__ __launch_bounds__(256) void k_dequant(const int* __restrict__ qw,
                                                 const int* __restrict__ qz,
                                                 const float* __restrict__ sc,
                                                 u16* __restrict__ W, int dout) {
    __shared__ u32 L[64][9];       // 64 rows x 8 words (+1 pad: breaks bank resonance)
    __shared__ float scl[64];
    __shared__ u32 zq[8];
    int tid = threadIdx.x;
    int w8 = dout >> 3;
    int c0 = blockIdx.x * 64, j0 = blockIdx.x * 8;
    int r0 = blockIdx.y * 64, g = r0 >> 7;       // G=128, r0%128 in {0,64} -> uniform
#pragma unroll
    for (int t = 0; t < 2; ++t) {
        int u = tid + t * 256;
        int rr = u >> 3, jj = u & 7;             // coalesced: 8 consecutive words/row
        L[rr][jj] = (u32)qw[(size_t)(r0 + rr) * w8 + j0 + jj];
    }
    if (tid < 64) scl[tid] = sc[(size_t)g * dout + c0 + tid];
    if (tid < 8)  zq[tid]  = (u32)qz[(size_t)g * w8 + j0 + tid];
    __syncthreads();
#pragma unroll
    for (int t = 0; t < 2; ++t) {
        int u = tid + t * 256;
        int lc = u >> 3, r8 = (u & 7) << 3;      // chunk: col c0+lc, rows r0+r8..+7
        int sh = (lc & 7) << 2, jc = lc >> 3;
        int z = (int)((zq[jc] >> sh) & 15u);
        float s = scl[lc];
        u16x8 v;
#pragma unroll
        for (int i = 0; i < 8; ++i) {
            int w = (int)((L[r8 + i][jc] >> sh) & 15u);
            v[i] = f2h((float)(w - z) * s);
        }
        *(u16x8*)(W + (size_t)(c0 + lc) * KD + r0 + r8) = v;
    }
}

// ---- fp16 MFMA GEMM (m97-style + T2 XOR-swizzle): C = A @ B^T + bias ----
// T2: 128B LDS row stride = 32 banks -> chunk16B ^= row&7 on BOTH sides.
// Measured R4: SQ_LDS_BANK_CONFLICT = 0.
// R6 lesson: XCD-chunked blockIdx remap INCREASED FETCH 124->183MB; linear
// order already time-shares one A-panel across XCDs via L3. Keep linear.
__global__ __launch_bounds__(256) void k_gemm_f16(const u16* __restrict__ A,
                                                  const u16* __restrict__ B,
                                                  const float* __restrict__ bias,
                                                  float* __restrict__ C,
                                                  float* __restrict__ Cp,
                                                  int M, int N, int K) {
    __shared__ __attribute__((aligned(16))) u16 Ash[128 * 64];
    __shared__ __attribute__((aligned(16))) u16 Bsh[128 * 64];
    int tid = threadIdx.x;
    int m0 = blockIdx.y * 128, n0 = blockIdx.x * 128;
    int klen = K / gridDim.z;
    int kbeg = blockIdx.z * klen, kend = kbeg + klen;
    int wave = tid >> 6, lane = tid & 63;
    int l16 = lane & 15, quad = lane >> 4;
    int wr = wave >> 1, wc = wave & 1;
    int lrow = lane >> 3, lcol = lane & 7;      // staging: 8 rows x 8 chunks(16B)
    int scol = lcol ^ lrow;                     // pre-swizzled source chunk
    int sw = l16 & 7;                           // read-side swizzle key (= row&7)

    f32x4 acc[4][4];
    f32x4 zero4 = {0.f, 0.f, 0.f, 0.f};
#pragma unroll
    for (int i = 0; i < 4; ++i)
#pragma unroll
        for (int j = 0; j < 4; ++j) acc[i][j] = zero4;

    for (int kk = kbeg; kk < kend; kk += 64) {
        __syncthreads();                         // WAR: prior ds_reads done
#pragma unroll
        for (int j = 0; j < 4; ++j) {
            int rbase = wave * 32 + j * 8;       // wave-uniform, 8-aligned
            size_t ga = (size_t)(m0 + rbase + lrow) * K + kk + scol * 8;
            size_t gb = (size_t)(n0 + rbase + lrow) * K + kk + scol * 8;
            GLL16(A + ga, &Ash[rbase * 64]);
            GLL16(B + gb, &Bsh[rbase * 64]);
        }
        __syncthreads();                         // vmcnt(0) drain -> data visible
#pragma unroll
        for (int kc = 0; kc < 2; ++kc) {
            f16x8 af[4], bv[4];
#pragma unroll
            for (int i = 0; i < 4; ++i)
                af[i] = *(const f16x8*)&Ash[(wr * 64 + i * 16 + l16) * 64
                                            + (((kc * 4 + quad) ^ sw) << 3)];
#pragma unroll
            for (int j = 0; j < 4; ++j)
                bv[j] = *(const f16x8*)&Bsh[(wc * 64 + j * 16 + l16) * 64
                                            + (((kc * 4 + quad) ^ sw) << 3)];
#pragma unroll
            for (int i = 0; i < 4; ++i)
#pragma unroll
                for (int j = 0; j < 4; ++j)
                    acc[i][j] = __builtin_amdgcn_mfma_f32_16x16x32_f16(af[i], bv[j], acc[i][j], 0, 0, 0);
        }
    }
    float* dst = (blockIdx.z == 0) ? C : Cp;
    bool addb = (bias != nullptr) && (blockIdx.z == 0);
#pragma unroll
    for (int i = 0; i < 4; ++i)
#pragma unroll
        for (int r = 0; r < 4; ++r) {
            int row = m0 + wr * 64 + i * 16 + quad * 4 + r;
#pragma unroll
            for (int j = 0; j < 4; ++j) {
                int col = n0 + wc * 64 + j * 16 + l16;
                float v = acc[i][j][r];
                if (addb) v += bias[col];
                dst[(size_t)row * N + col] = v;
            }
        }
}

// ---- out += partial (fp32, float4) ----
__global__ void k_reduce(float* __restrict__ out, const float* __restrict__ part, int n4) {
    int i = blockIdx.x * 256 + threadIdx.x;
    if (i >= n4) return;
    float4 a = ((const float4*)out)[i];
    float4 b = ((const float4*)part)[i];
    a.x += b.x; a.y += b.y; a.z += b.z; a.w += b.w;
    ((float4*)out)[i] = a;
}

// ---- RoPE (fp64 angles) -> Qh/Ql (S,3584), Kh (S,512) fp16 ----
// Pair restructure: each thread rotates the (d, d+64) PAIR, loading each
// Y/Yp element exactly once. Q pre-scaled by 1/sqrt(HD)*log2(e).
__global__ void k_rope2(const float* __restrict__ Y, const float* __restrict__ Yp,
                        const int* __restrict__ pos,
                        u16* __restrict__ Qh, u16* __restrict__ Ql,
                        u16* __restrict__ Kh) {
    __shared__ double finv[64];
    int tid = threadIdx.x;
    if (tid < 64)   // inv_freq = theta^(-i/64) = 2^(-i*log2(1e6)/64)
        finv[tid] = exp2(-0.3114307588956902 * (double)tid);
    __syncthreads();
    int s = blockIdx.x;
    double p = (double)pos[s];
    const float* y  = Y + (size_t)s * NQKV;
    const float* yp = Yp ? (Yp + (size_t)s * NQKV) : nullptr;
    const float QSCALE = 0.1275174313f;     // (1/sqrt(128)) * log2(e)
    for (int u = tid; u < 2048; u += 256) {
        int blk = u >> 6, i = u & 63;        // 128-wide head-half block, freq idx
        int idx  = blk * 128 + i;            // d = i (< 64)
        int idx2 = idx + 64;                 // d = i + 64 (same head block)
        double ang = p * finv[i];
        double n = rint(ang * 0.15915494309189535);          // /(2*pi)
        float r = (float)fma(-6.283185307179586, n, ang);    // range-reduced angle
        float sn, cs;
        __sincosf(r, &sn, &cs);
        float v1 = y[idx], v2 = y[idx2];
        if (yp) { v1 += yp[idx]; v2 += yp[idx2]; }
        float o1 = v1 * cs - v2 * sn;
        float o2 = v2 * cs + v1 * sn;
        if (idx < 3584) {
            u16 hh, ll;
            split2(o1 * QSCALE, hh, ll);
            Qh[(size_t)s * 3584 + idx] = hh;
            Ql[(size_t)s * 3584 + idx] = ll;
            split2(o2 * QSCALE, hh, ll);
            Qh[(size_t)s * 3584 + idx2] = hh;
            Ql[(size_t)s * 3584 + idx2] = ll;
        } else {
            Kh[(size_t)s * 512 + (idx  - 3584)] = f2h(o1);
            Kh[(size_t)s * 512 + (idx2 - 3584)] = f2h(o2);
        }
    }
}

// ---- transpose V section of Y: (S x 512) fp32 -> Vt (512 x S) fp16 ----
__global__ __launch_bounds__(256) void k_vtrans(const float* __restrict__ Y,
                                                const float* __restrict__ Yp,
                                                u16* __restrict__ Vt) {
    __shared__ __attribute__((aligned(16))) u16 T[64][72];
    int s0 = blockIdx.x * 64, d0 = blockIdx.y * 64;
    int tid = threadIdx.x;
#pragma unroll
    for (int t = 0; t < 16; ++t) {
        int idx = tid + t * 256;
        int r = idx >> 6, c = idx & 63;
        size_t goff = (size_t)(s0 + r) * NQKV + 4096 + d0 + c;
        float val = Y[goff];
        if (Yp) val += Yp[goff];
        T[c][r] = f2h(val);
    }
    __syncthreads();
#pragma unroll
    for (int t = 0; t < 2; ++t) {
        int cc = tid + t * 256;
        int dr = cc >> 3, s8 = (cc & 7) << 3;
        *(u16x8*)(Vt + (size_t)(d0 + dr) * Sq + s0 + s8) = *(const u16x8*)&T[dr][s8];
    }
}

// ---- flash attention fp16: persistent blocks, LPT queue, reg-prefetch ----
// EXACT R7-verified body (121us, VGPR 124, 4 blocks/CU). Lessons pinned:
//  R3: no min-waves clamp (VGPR squeeze -> full spill).
//  R5: no device fences / cross-block merge in-kernel (L2 churn).
//  R8: K/V LDS staging is SOFTWARE PREFETCH; direct-global loads serialize.
//  R9: VGPR=124 is 4 below the 128 occupancy cliff -- ANY added live state
//      (extra accumulator, ones-operand) drops a block/CU and loses ~50us.
//      Do not add registers to this kernel.
// LDS: XOR-swizzled power-of-2 tiles (chunk16B ^= row&7), 40960 B total.
// Softmax in log2 domain (Q pre-scaled at RoPE) + T13 defer-max + T5 setprio.
__global__ __launch_bounds__(256) void k_attn(const u16* __restrict__ Qh,
                                              const u16* __restrict__ Ql,
                                              const u16* __restrict__ Kh,
                                              const u16* __restrict__ Vt,
                                              u16* __restrict__ AO,
                                              int* __restrict__ ctr) {
    __shared__ __attribute__((aligned(16))) u16 Ks[64][128];   // 16384 B, swizzled
    __shared__ __attribute__((aligned(16))) u16 Vs[128][64];   // 16384 B, swizzled
    __shared__ __attribute__((aligned(16))) u16 Ps[4][16][64]; //  8192 B, swizzled

    int tid = threadIdx.x;
    int wave = tid >> 6, lane = tid & 63, l16 = lane & 15, quad = lane >> 4;
    int sw = l16 & 7;                       // read-side swizzle key (= row&7)

    for (;;) {
        __syncthreads();                   // all waves done with prior item
        if (tid == 0) *(int*)&Ks[0][0] = atomicAdd(ctr, 1);
        __syncthreads();
        int item = *(const int*)&Ks[0][0];
        if (item >= 32 * NH) break;        // block-uniform exit
        int qt = 31 - item / NH;           // longest first (LPT)
        int h  = item % NH;
        int q0 = qt * 64;
        int kvh = h / 7;                   // NH/NKV = 7
        __syncthreads();                   // item slot read by all before staging

        const u16* Kbase = Kh + kvh * HD;                  // row stride 512
        const u16* Vbase = Vt + (size_t)(kvh * HD) * Sq;   // row stride Sq

        // Q fragments hi/lo direct from global (A-layout: m=l16, k=quad*8+j)
        f16x8 qfh[4], qfl[4];
        {
            size_t qoff = (size_t)(q0 + wave * 16 + l16) * Hdim + h * HD + quad * 8;
#pragma unroll
            for (int kc = 0; kc < 4; ++kc) {
                qfh[kc] = *(const f16x8*)(Qh + qoff + kc * 32);
                qfl[kc] = *(const f16x8*)(Ql + qoff + kc * 32);
            }
        }

        // initial staging of tile 0 (swizzled writes)
#pragma unroll
        for (int t = 0; t < 4; ++t) {
            int c = tid + t * 256;
            int row = c >> 4, ch = (c & 15) ^ (row & 7);
            *(u16x8*)&Ks[row][ch << 3] = *(const u16x8*)(Kbase + (size_t)row * 512 + ((c & 15) << 3));
        }
#pragma unroll
        for (int t = 0; t < 4; ++t) {
            int c = tid + t * 256;
            int d = c >> 3, ch = (c & 7) ^ (d & 7);
            *(u16x8*)&Vs[d][ch << 3] = *(const u16x8*)(Vbase + (size_t)d * Sq + ((c & 7) << 3));
        }
        __syncthreads();

        f32x4 O[8];
        f32x4 zero4 = {0.f, 0.f, 0.f, 0.f};
#pragma unroll
        for (int t = 0; t < 8; ++t) O[t] = zero4;
        float mrow[4], lrow[4];
#pragma unroll
        for (int r = 0; r < 4; ++r) { mrow[r] = -1e30f; lrow[r] = 0.f; }

        for (int kt = 0; kt <= qt; ++kt) {
            int k0 = kt * 64;
            int kn = (kt < qt) ? k0 + 64 : k0;     // clamped prefetch base

            // ---- issue next-tile loads into registers (latency overlapped) ----
            u16x8 nk[4], nv[4];
#pragma unroll
            for (int t = 0; t < 4; ++t) {
                int c = tid + t * 256;
                nk[t] = *(const u16x8*)(Kbase + (size_t)(kn + (c >> 4)) * 512 + ((c & 15) << 3));
                nv[t] = *(const u16x8*)(Vbase + (size_t)(c >> 3) * Sq + kn + ((c & 7) << 3));
            }

            // ---- compute current tile from LDS (log2-domain scores) ----
            f32x4 sa[4];                       // S = Q K^T, 2-term split
            __builtin_amdgcn_s_setprio(1);
#pragma unroll
            for (int ct = 0; ct < 4; ++ct) {
                f32x4 z = zero4;
#pragma unroll
                for (int kc = 0; kc < 4; ++kc) {
                    f16x8 b = *(const f16x8*)&Ks[ct * 16 + l16][(((kc * 4 + quad) ^ sw)) << 3];
                    z = __builtin_amdgcn_mfma_f32_16x16x32_f16(qfh[kc], b, z, 0, 0, 0);
                    z = __builtin_amdgcn_mfma_f32_16x16x32_f16(qfl[kc], b, z, 0, 0, 0);
                }
                sa[ct] = z;
            }
            __builtin_amdgcn_s_setprio(0);
            if (kt == qt) {
#pragma unroll
                for (int ct = 0; ct < 4; ++ct)
#pragma unroll
                    for (int r = 0; r < 4; ++r)
                        if (k0 + ct * 16 + l16 > q0 + wave * 16 + quad * 4 + r) sa[ct][r] = -1e30f;
            }
            // row max of this tile
            float pmax[4];
#pragma unroll
            for (int r = 0; r < 4; ++r) {
                float mx = fmaxf(fmaxf(sa[0][r], sa[1][r]), fmaxf(sa[2][r], sa[3][r]));
#pragma unroll
                for (int off = 1; off < 16; off <<= 1)
                    mx = fmaxf(mx, __shfl_xor(mx, off, 64));
                pmax[r] = mx;
            }
            // T13 defer-max: skip rescale while max growth <= 8 (P <= 2^8)
            bool keep = (pmax[0] <= mrow[0] + 8.f) && (pmax[1] <= mrow[1] + 8.f) &&
                        (pmax[2] <= mrow[2] + 8.f) && (pmax[3] <= mrow[3] + 8.f);
            if (!__all(keep)) {
#pragma unroll
                for (int r = 0; r < 4; ++r) {
                    float mnew = fmaxf(mrow[r], pmax[r]);
                    float alpha = exp2f(mrow[r] - mnew);
                    mrow[r] = mnew;
                    lrow[r] *= alpha;
#pragma unroll
                    for (int ct = 0; ct < 8; ++ct) O[ct][r] *= alpha;
                }
            }
            float rs[4] = {0.f, 0.f, 0.f, 0.f};
#pragma unroll
            for (int ct = 0; ct < 4; ++ct)
#pragma unroll
                for (int r = 0; r < 4; ++r) {
                    float p = exp2f(sa[ct][r] - mrow[r]);
                    rs[r] += p;
                    // swizzled Ps write: chunk ^= row&7, row = quad*4+r
                    Ps[wave][quad * 4 + r][(ct * 16 + l16) ^ (((quad * 4 + r) & 7) << 3)] = f2h(p);
                }
#pragma unroll
            for (int r = 0; r < 4; ++r) {
#pragma unroll
                for (int off = 1; off < 16; off <<= 1)
                    rs[r] += __shfl_xor(rs[r], off, 64);
                lrow[r] += rs[r];
            }
            __builtin_amdgcn_s_setprio(1);
#pragma unroll
            for (int kc = 0; kc < 2; ++kc) {   // PV from LDS (Ps wave-private)
                f16x8 a = *(const f16x8*)&Ps[wave][l16][(((kc * 4 + quad) ^ sw)) << 3];
#pragma unroll
                for (int ct = 0; ct < 8; ++ct) {
                    f16x8 b = *(const f16x8*)&Vs[ct * 16 + l16][(((kc * 4 + quad) ^ sw)) << 3];
                    O[ct] = __builtin_amdgcn_mfma_f32_16x16x32_f16(a, b, O[ct], 0, 0, 0);
                }
            }
            __builtin_amdgcn_s_setprio(0);

            // ---- commit prefetched tile to LDS (swizzled) ----
            __syncthreads();                   // all waves done reading Ks/Vs
#pragma unroll
            for (int t = 0; t < 4; ++t) {
                int c = tid + t * 256;
                int row = c >> 4, chk = ((c & 15) ^ (row & 7));
                int d = c >> 3, chv = ((c & 7) ^ (d & 7));
                *(u16x8*)&Ks[row][chk << 3] = nk[t];
                *(u16x8*)&Vs[d][chv << 3]   = nv[t];
            }
            __syncthreads();                   // staged data visible
        }
#pragma unroll
        for (int r = 0; r < 4; ++r) {
            float inv = 1.f / lrow[r];
            int row = q0 + wave * 16 + quad * 4 + r;
#pragma unroll
            for (int ct = 0; ct < 8; ++ct)
                AO[(size_t)row * 3584 + h * HD + ct * 16 + l16] = f2h(O[ct][r] * inv);
        }
    }
}

extern "C" void kernel_launch(void* const* d_in, const int* in_sizes, int n_in,
                              void* d_out, int out_size, void* d_ws, size_t ws_size,
                              hipStream_t stream) {
    (void)in_sizes; (void)n_in; (void)out_size;
    const float* hidden = (const float*)d_in[0];
    const int*   pos    = (const int*)d_in[1];
    const int*   qw_q = (const int*)d_in[2];
    const int*   qz_q = (const int*)d_in[3];
    const float* sc_q = (const float*)d_in[4];
    const float* b_q  = (const float*)d_in[5];
    const int*   qw_k = (const int*)d_in[6];
    const int*   qz_k = (const int*)d_in[7];
    const float* sc_k = (const float*)d_in[8];
    const float* b_k  = (const float*)d_in[9];
    const int*   qw_v = (const int*)d_in[10];
    const int*   qz_v = (const int*)d_in[11];
    const float* sc_v = (const float*)d_in[12];
    const float* b_v  = (const float*)d_in[13];
    const int*   qw_o = (const int*)d_in[14];
    const int*   qz_o = (const int*)d_in[15];
    const float* sc_o = (const float*)d_in[16];
    float* out = (float*)d_out;

    char* base = (char*)d_ws;
    size_t off = 0;
    auto alloc = [&](size_t bytes) {
        char* p = base + off;
        off += (bytes + 255) & ~(size_t)255;
        return p;
    };
    u16* Wh = (u16*)alloc((size_t)NQKV * KD * 2);   // 33.0 MB (reused for W_o)
    u16* Xh = (u16*)alloc((size_t)Sq * Hdim * 2);   // 14.7 MB (reused as Qh, then partial)
    u16* Xl = (u16*)alloc((size_t)Sq * Hdim * 2);   // 14.7 MB (Ql, then partial)
    float* Y = (float*)alloc((size_t)Sq * NQKV * 4);// 37.7 MB (reused for AO)
    u16* Khb = (u16*)alloc((size_t)Sq * 512 * 2);   //  2.1 MB
    u16* Vt  = (u16*)alloc((size_t)512 * Sq * 2);   //  2.1 MB
    float* biasc = (float*)alloc(NQKV * 4);
    int*   ctr   = (int*)alloc(4096);               // attn work-queue counter
    // split-K partial for GEMM1 (live GEMM1 -> rope/vtrans); gated on ws_size
    float* Part1 = (float*)alloc((size_t)Sq * NQKV * 4);   // 37.7 MB
    bool deep = (off <= ws_size);
    u16* Qhb = Xh;                 // Xh dead after GEMM1
    u16* Qlb = Xl;
    u16* AO  = (u16*)Y;            // Y dead after rope/vtrans
    u16* Wo  = Wh;                 // Wh dead after GEMM1
    float* Part = (float*)Xh;      // Xh+Xl contiguous = 29.4 MB, dead after attn

    hipMemsetAsync(ctr, 0, 4096, stream);           // ws is re-poisoned each call
    k_cvt<<<3584, 256, 0, stream>>>(hidden, Xh, (Sq * Hdim) / 8);
    k_bias<<<18, 256, 0, stream>>>(b_q, b_k, b_v, biasc);
    k_dequant<<<dim3(3584 / 64, KD / 64), 256, 0, stream>>>(qw_q, qz_q, sc_q, Wh, 3584);
    k_dequant<<<dim3(512 / 64, KD / 64), 256, 0, stream>>>(qw_k, qz_k, sc_k, Wh + (size_t)3584 * KD, 512);
    k_dequant<<<dim3(512 / 64, KD / 64), 256, 0, stream>>>(qw_v, qz_v, sc_v, Wh + (size_t)4096 * KD, 512);
    // GEMM1: split-K=2 -> 1152 blocks = 4.5/CU; partial folded into rope/vtrans.
    if (deep) {
        k_gemm_f16<<<dim3(NQKV / 128, Sq / 128, 2), 256, 0, stream>>>(Xh, Wh, biasc, Y, Part1, Sq, NQKV, KD);
    } else {
        k_gemm_f16<<<dim3(NQKV / 128, Sq / 128, 1), 256, 0, stream>>>(Xh, Wh, biasc, Y, nullptr, Sq, NQKV, KD);
    }
    k_rope2<<<Sq, 256, 0, stream>>>(Y, deep ? Part1 : nullptr, pos, Qhb, Qlb, Khb);
    k_vtrans<<<dim3(Sq / 64, 512 / 64), 256, 0, stream>>>(Y, deep ? Part1 : nullptr, Vt);
    k_dequant<<<dim3(3584 / 64, KD / 64), 256, 0, stream>>>(qw_o, qz_o, sc_o, Wo, 3584);
    k_attn<<<dim3(1024), 256, 0, stream>>>(Qhb, Qlb, Khb, Vt, AO, ctr);
    k_gemm_f16<<<dim3(Hdim / 128, Sq / 128, 2), 256, 0, stream>>>(AO, Wo, nullptr, out, Part, Sq, Hdim, KD);
    k_reduce<<<(Sq * Hdim / 4 + 255) / 256, 256, 0, stream>>>(out, Part, Sq * Hdim / 4);
}

// Round 11
// 451.718 us; speedup vs baseline: 1.4224x; 1.0372x over previous
//
#include <hip/hip_runtime.h>

// ---- problem constants ----
#define Hdim   3584
#define NH     28
#define NKV    4
#define HD     128
#define Sq     2048
#define NQKV   4608          // 3584 q + 512 k + 512 v
#define KD     3584          // inner dim of both GEMMs

typedef unsigned short u16;
typedef unsigned int   u32;
typedef _Float16 f16;
typedef _Float16 f16x8 __attribute__((ext_vector_type(8)));     // MFMA A/B operand (4 VGPRs)
typedef unsigned short u16x8 __attribute__((ext_vector_type(8)));
typedef float f32x4 __attribute__((ext_vector_type(4)));        // MFMA C/D operand

__device__ __forceinline__ u16 f2h(float x) { f16 h = (f16)x; return __builtin_bit_cast(u16, h); }
__device__ __forceinline__ float h2f(u16 b) { return (float)__builtin_bit_cast(f16, b); }
__device__ __forceinline__ void split2(float x, u16& hi, u16& lo) {
    hi = f2h(x);
    lo = f2h(x - h2f(hi));   // combined ~22-bit mantissa
}

// async global->LDS, 16B per lane; LDS dest = wave-uniform base + lane*16
#define GLL16(gp, lp) __builtin_amdgcn_global_load_lds( \
    (__attribute__((address_space(1))) void*)(gp),      \
    (__attribute__((address_space(3))) void*)(lp), 16, 0, 0)

// ---- AWQ dequant tile body (R7-verified): 64x64 tile via coalesced LDS ----
__device__ __forceinline__ void deq_tile(const int* __restrict__ qw,
                                         const int* __restrict__ qz,
                                         const float* __restrict__ sc,
                                         u16* __restrict__ W, int dout,
                                         int bx, int by, int tid,
                                         u32 (*L)[9], float* scl, u32* zq) {
    int w8 = dout >> 3;
    int c0 = bx * 64, j0 = bx * 8;
    int r0 = by * 64, g = r0 >> 7;               // G=128 -> uniform per tile
#pragma unroll
    for (int t = 0; t < 2; ++t) {
        int u = tid + t * 256;
        int rr = u >> 3, jj = u & 7;             // coalesced: 8 consecutive words/row
        L[rr][jj] = (u32)qw[(size_t)(r0 + rr) * w8 + j0 + jj];
    }
    if (tid < 64) scl[tid] = sc[(size_t)g * dout + c0 + tid];
    if (tid < 8)  zq[tid]  = (u32)qz[(size_t)g * w8 + j0 + tid];
    __syncthreads();
#pragma unroll
    for (int t = 0; t < 2; ++t) {
        int u = tid + t * 256;
        int lc = u >> 3, r8 = (u & 7) << 3;      // chunk: col c0+lc, rows r0+r8..+7
        int sh = (lc & 7) << 2, jc = lc >> 3;
        int z = (int)((zq[jc] >> sh) & 15u);
        float s = scl[lc];
        u16x8 v;
#pragma unroll
        for (int i = 0; i < 8; ++i) {
            int w = (int)((L[r8 + i][jc] >> sh) & 15u);
            v[i] = f2h((float)(w - z) * s);
        }
        *(u16x8*)(W + (size_t)(c0 + lc) * KD + r0 + r8) = v;
    }
}

// ---- fused preprocessing: cvt | bias | deq_q | deq_k | deq_v | [deq_o] ----
// R11: 11 launches -> 7; each section body is byte-identical to its verified
// standalone kernel; sections are independent (deq_o gated: writes Wo2, a
// separate buffer, so it can run before GEMM1 reads Wh).
__global__ __launch_bounds__(256) void k_pre(const float* __restrict__ hidden,
                                             u16* __restrict__ Xh,
                                             const float* __restrict__ bq,
                                             const float* __restrict__ bk,
                                             const float* __restrict__ bv,
                                             float* __restrict__ biasc,
                                             const int* qwq, const int* qzq, const float* scq,
                                             const int* qwk, const int* qzk, const float* sck,
                                             const int* qwv, const int* qzv, const float* scv,
                                             const int* qwo, const int* qzo, const float* sco,
                                             u16* __restrict__ Wh,
                                             u16* __restrict__ Wo2) {
    __shared__ u32 L[64][9];
    __shared__ float scl[64];
    __shared__ u32 zq[8];
    int b = blockIdx.x, tid = threadIdx.x;
    if (b < 3584) {                              // fp32 -> fp16, 8 elems/thread
        int i = b * 256 + tid;                   // exactly Sq*Hdim/8 threads
        const float4* p = (const float4*)(hidden + (size_t)i * 8);
        float4 a = p[0], c = p[1];
        float v[8] = {a.x, a.y, a.z, a.w, c.x, c.y, c.z, c.w};
        u16x8 h;
#pragma unroll
        for (int j = 0; j < 8; ++j) h[j] = f2h(v[j]);
        *(u16x8*)(Xh + (size_t)i * 8) = h;
        return;
    }
    b -= 3584;
    if (b < 18) {                                // concat biases (q|k|v)
        int i = b * 256 + tid;
        if (i < NQKV)
            biasc[i] = (i < 3584) ? bq[i] : (i < 4096 ? bk[i - 3584] : bv[i - 4096]);
        return;
    }
    b -= 18;
    if (b < 3136) { deq_tile(qwq, qzq, scq, Wh, 3584, b % 56, b / 56, tid, L, scl, zq); return; }
    b -= 3136;
    if (b < 448)  { deq_tile(qwk, qzk, sck, Wh + (size_t)3584 * KD, 512, b % 8, b / 8, tid, L, scl, zq); return; }
    b -= 448;
    if (b < 448)  { deq_tile(qwv, qzv, scv, Wh + (size_t)4096 * KD, 512, b % 8, b / 8, tid, L, scl, zq); return; }
    b -= 448;
    deq_tile(qwo, qzo, sco, Wo2, 3584, b % 56, b / 56, tid, L, scl, zq);   // grid excludes when Wo2==null
}

// ---- standalone dequant (fallback when Wo2 doesn't fit the workspace) ----
__global__ __launch_bounds__(256) void k_dequant(const int* __restrict__ qw,
                                                 const int* __restrict__ qz,
                                                 const float* __restrict__ sc,
                                                 u16* __restrict__ W, int dout) {
    __shared__ u32 L[64][9];
    __shared__ float scl[64];
    __shared__ u32 zq[8];
    deq_tile(qw, qz, sc, W, dout, blockIdx.x, blockIdx.y, threadIdx.x, L, scl, zq);
}

// ---- fp16 MFMA GEMM (m97-style + T2 XOR-swizzle): C = A @ B^T + bias ----
// T2: 128B LDS row stride = 32 banks -> chunk16B ^= row&7 on BOTH sides.
// Measured R4: SQ_LDS_BANK_CONFLICT = 0.
// R6 lesson: XCD-chunked blockIdx remap INCREASED FETCH 124->183MB; linear
// order already time-shares one A-panel across XCDs via L3. Keep linear.
__global__ __launch_bounds__(256) void k_gemm_f16(const u16* __restrict__ A,
                                                  const u16* __restrict__ B,
                                                  const float* __restrict__ bias,
                                                  float* __restrict__ C,
                                                  float* __restrict__ Cp,
                                                  int M, int N, int K) {
    __shared__ __attribute__((aligned(16))) u16 Ash[128 * 64];
    __shared__ __attribute__((aligned(16))) u16 Bsh[128 * 64];
    int tid = threadIdx.x;
    int m0 = blockIdx.y * 128, n0 = blockIdx.x * 128;
    int klen = K / gridDim.z;
    int kbeg = blockIdx.z * klen, kend = kbeg + klen;
    int wave = tid >> 6, lane = tid & 63;
    int l16 = lane & 15, quad = lane >> 4;
    int wr = wave >> 1, wc = wave & 1;
    int lrow = lane >> 3, lcol = lane & 7;      // staging: 8 rows x 8 chunks(16B)
    int scol = lcol ^ lrow;                     // pre-swizzled source chunk
    int sw = l16 & 7;                           // read-side swizzle key (= row&7)

    f32x4 acc[4][4];
    f32x4 zero4 = {0.f, 0.f, 0.f, 0.f};
#pragma unroll
    for (int i = 0; i < 4; ++i)
#pragma unroll
        for (int j = 0; j < 4; ++j) acc[i][j] = zero4;

    for (int kk = kbeg; kk < kend; kk += 64) {
        __syncthreads();                         // WAR: prior ds_reads done
#pragma unroll
        for (int j = 0; j < 4; ++j) {
            int rbase = wave * 32 + j * 8;       // wave-uniform, 8-aligned
            size_t ga = (size_t)(m0 + rbase + lrow) * K + kk + scol * 8;
            size_t gb = (size_t)(n0 + rbase + lrow) * K + kk + scol * 8;
            GLL16(A + ga, &Ash[rbase * 64]);
            GLL16(B + gb, &Bsh[rbase * 64]);
        }
        __syncthreads();                         // vmcnt(0) drain -> data visible
#pragma unroll
        for (int kc = 0; kc < 2; ++kc) {
            f16x8 af[4], bv[4];
#pragma unroll
            for (int i = 0; i < 4; ++i)
                af[i] = *(const f16x8*)&Ash[(wr * 64 + i * 16 + l16) * 64
                                            + (((kc * 4 + quad) ^ sw) << 3)];
#pragma unroll
            for (int j = 0; j < 4; ++j)
                bv[j] = *(const f16x8*)&Bsh[(wc * 64 + j * 16 + l16) * 64
                                            + (((kc * 4 + quad) ^ sw) << 3)];
#pragma unroll
            for (int i = 0; i < 4; ++i)
#pragma unroll
                for (int j = 0; j < 4; ++j)
                    acc[i][j] = __builtin_amdgcn_mfma_f32_16x16x32_f16(af[i], bv[j], acc[i][j], 0, 0, 0);
        }
    }
    float* dst = (blockIdx.z == 0) ? C : Cp;
    bool addb = (bias != nullptr) && (blockIdx.z == 0);
#pragma unroll
    for (int i = 0; i < 4; ++i)
#pragma unroll
        for (int r = 0; r < 4; ++r) {
            int row = m0 + wr * 64 + i * 16 + quad * 4 + r;
#pragma unroll
            for (int j = 0; j < 4; ++j) {
                int col = n0 + wc * 64 + j * 16 + l16;
                float v = acc[i][j][r];
                if (addb) v += bias[col];
                dst[(size_t)row * N + col] = v;
            }
        }
}

// ---- out += partial (fp32, float4) ----
__global__ void k_reduce(float* __restrict__ out, const float* __restrict__ part, int n4) {
    int i = blockIdx.x * 256 + threadIdx.x;
    if (i >= n4) return;
    float4 a = ((const float4*)out)[i];
    float4 b = ((const float4*)part)[i];
    a.x += b.x; a.y += b.y; a.z += b.z; a.w += b.w;
    ((float4*)out)[i] = a;
}

// ---- fused RoPE + V-transpose (disjoint column ranges of Y) ----
// blocks 0..2047: rope row s (pair restructure, fp64 angles, Q pre-scaled by
// 1/sqrt(HD)*log2(e) -> scores exit QK^T in log2 domain).
// blocks 2048..2303: vtrans 64x64 tile (R10-verified body).
__global__ __launch_bounds__(256) void k_ropevt(const float* __restrict__ Y,
                                                const float* __restrict__ Yp,
                                                const int* __restrict__ pos,
                                                u16* __restrict__ Qh, u16* __restrict__ Ql,
                                                u16* __restrict__ Kh,
                                                u16* __restrict__ Vt) {
    int tid = threadIdx.x;
    if (blockIdx.x < 2048) {
        __shared__ double finv[64];
        if (tid < 64)   // inv_freq = theta^(-i/64) = 2^(-i*log2(1e6)/64)
            finv[tid] = exp2(-0.3114307588956902 * (double)tid);
        __syncthreads();
        int s = blockIdx.x;
        double p = (double)pos[s];
        const float* y  = Y + (size_t)s * NQKV;
        const float* yp = Yp ? (Yp + (size_t)s * NQKV) : nullptr;
        const float QSCALE = 0.1275174313f;     // (1/sqrt(128)) * log2(e)
        for (int u = tid; u < 2048; u += 256) {
            int blk = u >> 6, i = u & 63;        // 128-wide head block, freq idx
            int idx  = blk * 128 + i;            // d = i (< 64)
            int idx2 = idx + 64;                 // d = i + 64 (same head block)
            double ang = p * finv[i];
            double n = rint(ang * 0.15915494309189535);          // /(2*pi)
            float r = (float)fma(-6.283185307179586, n, ang);    // range-reduced angle
            float sn, cs;
            __sincosf(r, &sn, &cs);
            float v1 = y[idx], v2 = y[idx2];
            if (yp) { v1 += yp[idx]; v2 += yp[idx2]; }
            float o1 = v1 * cs - v2 * sn;
            float o2 = v2 * cs + v1 * sn;
            if (idx < 3584) {
                u16 hh, ll;
                split2(o1 * QSCALE, hh, ll);
                Qh[(size_t)s * 3584 + idx] = hh;
                Ql[(size_t)s * 3584 + idx] = ll;
                split2(o2 * QSCALE, hh, ll);
                Qh[(size_t)s * 3584 + idx2] = hh;
                Ql[(size_t)s * 3584 + idx2] = ll;
            } else {
                Kh[(size_t)s * 512 + (idx  - 3584)] = f2h(o1);
                Kh[(size_t)s * 512 + (idx2 - 3584)] = f2h(o2);
            }
        }
    } else {
        __shared__ __attribute__((aligned(16))) u16 T[64][72];
        int local = blockIdx.x - 2048;
        int s0 = (local % 32) * 64, d0 = (local / 32) * 64;
#pragma unroll
        for (int t = 0; t < 16; ++t) {
            int idx = tid + t * 256;
            int r = idx >> 6, c = idx & 63;
            size_t goff = (size_t)(s0 + r) * NQKV + 4096 + d0 + c;
            float val = Y[goff];
            if (Yp) val += Yp[goff];
            T[c][r] = f2h(val);
        }
        __syncthreads();
#pragma unroll
        for (int t = 0; t < 2; ++t) {
            int cc = tid + t * 256;
            int dr = cc >> 3, s8 = (cc & 7) << 3;
            *(u16x8*)(Vt + (size_t)(d0 + dr) * Sq + s0 + s8) = *(const u16x8*)&T[dr][s8];
        }
    }
}

// ---- flash attention fp16: persistent blocks, LPT queue, reg-prefetch ----
// EXACT R7-verified body (121us, VGPR 124, 4 blocks/CU). Lessons pinned:
//  R3: no min-waves clamp (VGPR squeeze -> full spill).
//  R5: no device fences / cross-block merge in-kernel (L2 churn).
//  R8: K/V LDS staging is SOFTWARE PREFETCH; direct-global loads serialize.
//  R9: VGPR=124 is 4 below the 128 occupancy cliff -- ANY added live state
//      drops a block/CU and loses ~50us. Do not add registers.
// LDS: XOR-swizzled power-of-2 tiles (chunk16B ^= row&7), 40960 B total.
// Softmax in log2 domain (Q pre-scaled at RoPE) + T13 defer-max + T5 setprio.
__global__ __launch_bounds__(256) void k_attn(const u16* __restrict__ Qh,
                                              const u16* __restrict__ Ql,
                                              const u16* __restrict__ Kh,
                                              const u16* __restrict__ Vt,
                                              u16* __restrict__ AO,
                                              int* __restrict__ ctr) {
    __shared__ __attribute__((aligned(16))) u16 Ks[64][128];   // 16384 B, swizzled
    __shared__ __attribute__((aligned(16))) u16 Vs[128][64];   // 16384 B, swizzled
    __shared__ __attribute__((aligned(16))) u16 Ps[4][16][64]; //  8192 B, swizzled

    int tid = threadIdx.x;
    int wave = tid >> 6, lane = tid & 63, l16 = lane & 15, quad = lane >> 4;
    int sw = l16 & 7;                       // read-side swizzle key (= row&7)

    for (;;) {
        __syncthreads();                   // all waves done with prior item
        if (tid == 0) *(int*)&Ks[0][0] = atomicAdd(ctr, 1);
        __syncthreads();
        int item = *(const int*)&Ks[0][0];
        if (item >= 32 * NH) break;        // block-uniform exit
        int qt = 31 - item / NH;           // longest first (LPT)
        int h  = item % NH;
        int q0 = qt * 64;
        int kvh = h / 7;                   // NH/NKV = 7
        __syncthreads();                   // item slot read by all before staging

        const u16* Kbase = Kh + kvh * HD;                  // row stride 512
        const u16* Vbase = Vt + (size_t)(kvh * HD) * Sq;   // row stride Sq

        // Q fragments hi/lo direct from global (A-layout: m=l16, k=quad*8+j)
        f16x8 qfh[4], qfl[4];
        {
            size_t qoff = (size_t)(q0 + wave * 16 + l16) * Hdim + h * HD + quad * 8;
#pragma unroll
            for (int kc = 0; kc < 4; ++kc) {
                qfh[kc] = *(const f16x8*)(Qh + qoff + kc * 32);
                qfl[kc] = *(const f16x8*)(Ql + qoff + kc * 32);
            }
        }

        // initial staging of tile 0 (swizzled writes)
#pragma unroll
        for (int t = 0; t < 4; ++t) {
            int c = tid + t * 256;
            int row = c >> 4, ch = (c & 15) ^ (row & 7);
            *(u16x8*)&Ks[row][ch << 3] = *(const u16x8*)(Kbase + (size_t)row * 512 + ((c & 15) << 3));
        }
#pragma unroll
        for (int t = 0; t < 4; ++t) {
            int c = tid + t * 256;
            int d = c >> 3, ch = (c & 7) ^ (d & 7);
            *(u16x8*)&Vs[d][ch << 3] = *(const u16x8*)(Vbase + (size_t)d * Sq + ((c & 7) << 3));
        }
        __syncthreads();

        f32x4 O[8];
        f32x4 zero4 = {0.f, 0.f, 0.f, 0.f};
#pragma unroll
        for (int t = 0; t < 8; ++t) O[t] = zero4;
        float mrow[4], lrow[4];
#pragma unroll
        for (int r = 0; r < 4; ++r) { mrow[r] = -1e30f; lrow[r] = 0.f; }

        for (int kt = 0; kt <= qt; ++kt) {
            int k0 = kt * 64;
            int kn = (kt < qt) ? k0 + 64 : k0;     // clamped prefetch base

            // ---- issue next-tile loads into registers (latency overlapped) ----
            u16x8 nk[4], nv[4];
#pragma unroll
            for (int t = 0; t < 4; ++t) {
                int c = tid + t * 256;
                nk[t] = *(const u16x8*)(Kbase + (size_t)(kn + (c >> 4)) * 512 + ((c & 15) << 3));
                nv[t] = *(const u16x8*)(Vbase + (size_t)(c >> 3) * Sq + kn + ((c & 7) << 3));
            }

            // ---- compute current tile from LDS (log2-domain scores) ----
            f32x4 sa[4];                       // S = Q K^T, 2-term split
            __builtin_amdgcn_s_setprio(1);
#pragma unroll
            for (int ct = 0; ct < 4; ++ct) {
                f32x4 z = zero4;
#pragma unroll
                for (int kc = 0; kc < 4; ++kc) {
                    f16x8 b = *(const f16x8*)&Ks[ct * 16 + l16][(((kc * 4 + quad) ^ sw)) << 3];
                    z = __builtin_amdgcn_mfma_f32_16x16x32_f16(qfh[kc], b, z, 0, 0, 0);
                    z = __builtin_amdgcn_mfma_f32_16x16x32_f16(qfl[kc], b, z, 0, 0, 0);
                }
                sa[ct] = z;
            }
            __builtin_amdgcn_s_setprio(0);
            if (kt == qt) {
#pragma unroll
                for (int ct = 0; ct < 4; ++ct)
#pragma unroll
                    for (int r = 0; r < 4; ++r)
                        if (k0 + ct * 16 + l16 > q0 + wave * 16 + quad * 4 + r) sa[ct][r] = -1e30f;
            }
            // row max of this tile
            float pmax[4];
#pragma unroll
            for (int r = 0; r < 4; ++r) {
                float mx = fmaxf(fmaxf(sa[0][r], sa[1][r]), fmaxf(sa[2][r], sa[3][r]));
#pragma unroll
                for (int off = 1; off < 16; off <<= 1)
                    mx = fmaxf(mx, __shfl_xor(mx, off, 64));
                pmax[r] = mx;
            }
            // T13 defer-max: skip rescale while max growth <= 8 (P <= 2^8)
            bool keep = (pmax[0] <= mrow[0] + 8.f) && (pmax[1] <= mrow[1] + 8.f) &&
                        (pmax[2] <= mrow[2] + 8.f) && (pmax[3] <= mrow[3] + 8.f);
            if (!__all(keep)) {
#pragma unroll
                for (int r = 0; r < 4; ++r) {
                    float mnew = fmaxf(mrow[r], pmax[r]);
                    float alpha = exp2f(mrow[r] - mnew);
                    mrow[r] = mnew;
                    lrow[r] *= alpha;
#pragma unroll
                    for (int ct = 0; ct < 8; ++ct) O[ct][r] *= alpha;
                }
            }
            float rs[4] = {0.f, 0.f, 0.f, 0.f};
#pragma unroll
            for (int ct = 0; ct < 4; ++ct)
#pragma unroll
                for (int r = 0; r < 4; ++r) {
                    float p = exp2f(sa[ct][r] - mrow[r]);
                    rs[r] += p;
                    // swizzled Ps write: chunk ^= row&7, row = quad*4+r
                    Ps[wave][quad * 4 + r][(ct * 16 + l16) ^ (((quad * 4 + r) & 7) << 3)] = f2h(p);
                }
#pragma unroll
            for (int r = 0; r < 4; ++r) {
#pragma unroll
                for (int off = 1; off < 16; off <<= 1)
                    rs[r] += __shfl_xor(rs[r], off, 64);
                lrow[r] += rs[r];
            }
            __builtin_amdgcn_s_setprio(1);
#pragma unroll
            for (int kc = 0; kc < 2; ++kc) {   // PV from LDS (Ps wave-private)
                f16x8 a = *(const f16x8*)&Ps[wave][l16][(((kc * 4 + quad) ^ sw)) << 3];
#pragma unroll
                for (int ct = 0; ct < 8; ++ct) {
                    f16x8 b = *(const f16x8*)&Vs[ct * 16 + l16][(((kc * 4 + quad) ^ sw)) << 3];
                    O[ct] = __builtin_amdgcn_mfma_f32_16x16x32_f16(a, b, O[ct], 0, 0, 0);
                }
            }
            __builtin_amdgcn_s_setprio(0);

            // ---- commit prefetched tile to LDS (swizzled) ----
            __syncthreads();                   // all waves done reading Ks/Vs
#pragma unroll
            for (int t = 0; t < 4; ++t) {
                int c = tid + t * 256;
                int row = c >> 4, chk = ((c & 15) ^ (row & 7));
                int d = c >> 3, chv = ((c & 7) ^ (d & 7));
                *(u16x8*)&Ks[row][chk << 3] = nk[t];
                *(u16x8*)&Vs[d][chv << 3]   = nv[t];
            }
            __syncthreads();                   // staged data visible
        }
#pragma unroll
        for (int r = 0; r < 4; ++r) {
            float inv = 1.f / lrow[r];
            int row = q0 + wave * 16 + quad * 4 + r;
#pragma unroll
            for (int ct = 0; ct < 8; ++ct)
                AO[(size_t)row * 3584 + h * HD + ct * 16 + l16] = f2h(O[ct][r] * inv);
        }
    }
}

extern "C" void kernel_launch(void* const* d_in, const int* in_sizes, int n_in,
                              void* d_out, int out_size, void* d_ws, size_t ws_size,
                              hipStream_t stream) {
    (void)in_sizes; (void)n_in; (void)out_size;
    const float* hidden = (const float*)d_in[0];
    const int*   pos    = (const int*)d_in[1];
    const int*   qw_q = (const int*)d_in[2];
    const int*   qz_q = (const int*)d_in[3];
    const float* sc_q = (const float*)d_in[4];
    const float* b_q  = (const float*)d_in[5];
    const int*   qw_k = (const int*)d_in[6];
    const int*   qz_k = (const int*)d_in[7];
    const float* sc_k = (const float*)d_in[8];
    const float* b_k  = (const float*)d_in[9];
    const int*   qw_v = (const int*)d_in[10];
    const int*   qz_v = (const int*)d_in[11];
    const float* sc_v = (const float*)d_in[12];
    const float* b_v  = (const float*)d_in[13];
    const int*   qw_o = (const int*)d_in[14];
    const int*   qz_o = (const int*)d_in[15];
    const float* sc_o = (const float*)d_in[16];
    float* out = (float*)d_out;

    char* base = (char*)d_ws;
    size_t off = 0;
    auto alloc = [&](size_t bytes) {
        char* p = base + off;
        off += (bytes + 255) & ~(size_t)255;
        return p;
    };
    u16* Wh = (u16*)alloc((size_t)NQKV * KD * 2);   // 33.0 MB (reused for W_o fallback)
    u16* Xh = (u16*)alloc((size_t)Sq * Hdim * 2);   // 14.7 MB (reused as Qh, then partial)
    u16* Xl = (u16*)alloc((size_t)Sq * Hdim * 2);   // 14.7 MB (Ql, then partial)
    float* Y = (float*)alloc((size_t)Sq * NQKV * 4);// 37.7 MB (reused for AO)
    u16* Khb = (u16*)alloc((size_t)Sq * 512 * 2);   //  2.1 MB
    u16* Vt  = (u16*)alloc((size_t)512 * Sq * 2);   //  2.1 MB
    float* biasc = (float*)alloc(NQKV * 4);
    int*   ctr   = (int*)alloc(4096);               // attn work-queue counter
    // split-K partial for GEMM1 (live GEMM1 -> rope/vtrans); gated on ws_size
    float* Part1 = (float*)alloc((size_t)Sq * NQKV * 4);   // 37.7 MB
    bool deep = (off <= ws_size);
    // separate W_o buffer lets deq_o run in preprocessing (before GEMM1)
    u16* Wo2 = (u16*)alloc((size_t)3584 * KD * 2);  // 25.7 MB
    bool deep2 = (off <= ws_size);
    u16* Qhb = Xh;                 // Xh dead after GEMM1
    u16* Qlb = Xl;
    u16* AO  = (u16*)Y;            // Y dead after rope/vtrans
    u16* Wo  = Wh;                 // Wh dead after GEMM1 (fallback W_o dst)
    float* Part = (float*)Xh;      // Xh+Xl contiguous = 29.4 MB, dead after attn

    hipMemsetAsync(ctr, 0, 4096, stream);           // ws is re-poisoned each call
    // fused preprocessing: cvt(3584) | bias(18) | deq_q(3136) | deq_k(448)
    //                    | deq_v(448) | deq_o(3136, only if deep2)
    int preBlocks = 3584 + 18 + 3136 + 448 + 448 + (deep2 ? 3136 : 0);
    k_pre<<<preBlocks, 256, 0, stream>>>(hidden, Xh, b_q, b_k, b_v, biasc,
                                         qw_q, qz_q, sc_q, qw_k, qz_k, sc_k,
                                         qw_v, qz_v, sc_v, qw_o, qz_o, sc_o,
                                         Wh, deep2 ? Wo2 : nullptr);
    // GEMM1: split-K=2 -> 1152 blocks = 4.5/CU; partial folded into rope/vtrans.
    if (deep) {
        k_gemm_f16<<<dim3(NQKV / 128, Sq / 128, 2), 256, 0, stream>>>(Xh, Wh, biasc, Y, Part1, Sq, NQKV, KD);
    } else {
        k_gemm_f16<<<dim3(NQKV / 128, Sq / 128, 1), 256, 0, stream>>>(Xh, Wh, biasc, Y, nullptr, Sq, NQKV, KD);
    }
    k_ropevt<<<2304, 256, 0, stream>>>(Y, deep ? Part1 : nullptr, pos, Qhb, Qlb, Khb, Vt);
    if (!deep2)   // fallback: dequant W_o into Wh after GEMM1 consumed it
        k_dequant<<<dim3(56, 56), 256, 0, stream>>>(qw_o, qz_o, sc_o, Wo, 3584);
    k_attn<<<dim3(1024), 256, 0, stream>>>(Qhb, Qlb, Khb, Vt, AO, ctr);
    k_gemm_f16<<<dim3(Hdim / 128, Sq / 128, 2), 256, 0, stream>>>(AO, deep2 ? Wo2 : Wo, nullptr, out, Part, Sq, Hdim, KD);
    k_reduce<<<(Sq * Hdim / 4 + 255) / 256, 256, 0, stream>>>(out, Part, Sq * Hdim / 4);
}

// Round 12
// 447.911 us; speedup vs baseline: 1.4345x; 1.0085x over previous
//
#include <hip/hip_runtime.h>

// ---- problem constants ----
#define Hdim   3584
#define NH     28
#define NKV    4
#define HD     128
#define Sq     2048
#define NQKV   4608          // 3584 q + 512 k + 512 v
#define KD     3584          // inner dim of both GEMMs

typedef unsigned short u16;
typedef unsigned int   u32;
typedef _Float16 f16;
typedef _Float16 f16x8 __attribute__((ext_vector_type(8)));     // MFMA A/B operand (4 VGPRs)
typedef unsigned short u16x8 __attribute__((ext_vector_type(8)));
typedef float f32x4 __attribute__((ext_vector_type(4)));        // MFMA C/D operand

__device__ __forceinline__ u16 f2h(float x) { f16 h = (f16)x; return __builtin_bit_cast(u16, h); }
__device__ __forceinline__ float h2f(u16 b) { return (float)__builtin_bit_cast(f16, b); }
__device__ __forceinline__ void split2(float x, u16& hi, u16& lo) {
    hi = f2h(x);
    lo = f2h(x - h2f(hi));   // combined ~22-bit mantissa
}

// async global->LDS, 16B per lane; LDS dest = wave-uniform base + lane*16
#define GLL16(gp, lp) __builtin_amdgcn_global_load_lds( \
    (__attribute__((address_space(1))) void*)(gp),      \
    (__attribute__((address_space(3))) void*)(lp), 16, 0, 0)

// ---- AWQ dequant tile body (R7-verified): 64x64 tile via coalesced LDS ----
__device__ __forceinline__ void deq_tile(const int* __restrict__ qw,
                                         const int* __restrict__ qz,
                                         const float* __restrict__ sc,
                                         u16* __restrict__ W, int dout,
                                         int bx, int by, int tid,
                                         u32 (*L)[9], float* scl, u32* zq) {
    int w8 = dout >> 3;
    int c0 = bx * 64, j0 = bx * 8;
    int r0 = by * 64, g = r0 >> 7;               // G=128 -> uniform per tile
#pragma unroll
    for (int t = 0; t < 2; ++t) {
        int u = tid + t * 256;
        int rr = u >> 3, jj = u & 7;             // coalesced: 8 consecutive words/row
        L[rr][jj] = (u32)qw[(size_t)(r0 + rr) * w8 + j0 + jj];
    }
    if (tid < 64) scl[tid] = sc[(size_t)g * dout + c0 + tid];
    if (tid < 8)  zq[tid]  = (u32)qz[(size_t)g * w8 + j0 + tid];
    __syncthreads();
#pragma unroll
    for (int t = 0; t < 2; ++t) {
        int u = tid + t * 256;
        int lc = u >> 3, r8 = (u & 7) << 3;      // chunk: col c0+lc, rows r0+r8..+7
        int sh = (lc & 7) << 2, jc = lc >> 3;
        int z = (int)((zq[jc] >> sh) & 15u);
        float s = scl[lc];
        u16x8 v;
#pragma unroll
        for (int i = 0; i < 8; ++i) {
            int w = (int)((L[r8 + i][jc] >> sh) & 15u);
            v[i] = f2h((float)(w - z) * s);
        }
        *(u16x8*)(W + (size_t)(c0 + lc) * KD + r0 + r8) = v;
    }
}

// ---- fused preprocessing: cvt | bias | deq_q | deq_k | deq_v | [deq_o] ----
__global__ __launch_bounds__(256) void k_pre(const float* __restrict__ hidden,
                                             u16* __restrict__ Xh,
                                             const float* __restrict__ bq,
                                             const float* __restrict__ bk,
                                             const float* __restrict__ bv,
                                             float* __restrict__ biasc,
                                             const int* qwq, const int* qzq, const float* scq,
                                             const int* qwk, const int* qzk, const float* sck,
                                             const int* qwv, const int* qzv, const float* scv,
                                             const int* qwo, const int* qzo, const float* sco,
                                             u16* __restrict__ Wh,
                                             u16* __restrict__ Wo2) {
    __shared__ u32 L[64][9];
    __shared__ float scl[64];
    __shared__ u32 zq[8];
    int b = blockIdx.x, tid = threadIdx.x;
    if (b < 3584) {                              // fp32 -> fp16, 8 elems/thread
        int i = b * 256 + tid;
        const float4* p = (const float4*)(hidden + (size_t)i * 8);
        float4 a = p[0], c = p[1];
        float v[8] = {a.x, a.y, a.z, a.w, c.x, c.y, c.z, c.w};
        u16x8 h;
#pragma unroll
        for (int j = 0; j < 8; ++j) h[j] = f2h(v[j]);
        *(u16x8*)(Xh + (size_t)i * 8) = h;
        return;
    }
    b -= 3584;
    if (b < 18) {                                // concat biases (q|k|v)
        int i = b * 256 + tid;
        if (i < NQKV)
            biasc[i] = (i < 3584) ? bq[i] : (i < 4096 ? bk[i - 3584] : bv[i - 4096]);
        return;
    }
    b -= 18;
    if (b < 3136) { deq_tile(qwq, qzq, scq, Wh, 3584, b % 56, b / 56, tid, L, scl, zq); return; }
    b -= 3136;
    if (b < 448)  { deq_tile(qwk, qzk, sck, Wh + (size_t)3584 * KD, 512, b % 8, b / 8, tid, L, scl, zq); return; }
    b -= 448;
    if (b < 448)  { deq_tile(qwv, qzv, scv, Wh + (size_t)4096 * KD, 512, b % 8, b / 8, tid, L, scl, zq); return; }
    b -= 448;
    deq_tile(qwo, qzo, sco, Wo2, 3584, b % 56, b / 56, tid, L, scl, zq);
}

// ---- standalone dequant (fallback when Wo2 doesn't fit the workspace) ----
__global__ __launch_bounds__(256) void k_dequant(const int* __restrict__ qw,
                                                 const int* __restrict__ qz,
                                                 const float* __restrict__ sc,
                                                 u16* __restrict__ W, int dout) {
    __shared__ u32 L[64][9];
    __shared__ float scl[64];
    __shared__ u32 zq[8];
    deq_tile(qw, qz, sc, W, dout, blockIdx.x, blockIdx.y, threadIdx.x, L, scl, zq);
}

// ---- fp16 MFMA GEMM, 256x256 tile, counted-vmcnt pipeline (T2+T3+T4+T5) ----
// R12: the old 2-barrier 128x128 loop measured ~555 TF = the documented
// 2-phase structural ceiling (m233: 607 TF; stall = __syncthreads drains
// vmcnt every K-step). This kernel never drains vmcnt in the main loop:
//   iter t: issue tile t+1's 8 global_load_lds into the OTHER slot
//           -> s_waitcnt vmcnt(8)  (tile t landed; t+1's 8 stay in flight)
//           -> raw s_barrier -> 24 swizzled ds_read_b128 + 64 MFMA (setprio)
//           -> raw s_barrier (slot-reuse guard; no vmcnt drain).
// Race-freedom: staged slot != read slot (parity); stage issue for t+1 sits
// after t-1's end barrier (its slot fully consumed); sched_barrier(0) pins
// ordering around raw barriers (rule 18). Swizzle = R4-verified both-sides
// scheme (chunk16B ^= row&7; row bases 8-aligned). 512 thr = 8 waves (2Mx4N),
// per-wave output 128x64, LDS 128KB = 2 slots, 1 block/CU.
__global__ __launch_bounds__(512) void k_gemm256(const u16* __restrict__ A,
                                                 const u16* __restrict__ B,
                                                 const float* __restrict__ bias,
                                                 float* __restrict__ C,
                                                 float* __restrict__ Cp,
                                                 int M, int N, int K) {
    __shared__ __attribute__((aligned(16))) u16 Ash[2][256 * 64];
    __shared__ __attribute__((aligned(16))) u16 Bsh[2][256 * 64];
    int tid = threadIdx.x;
    int m0 = blockIdx.y * 256, n0 = blockIdx.x * 256;
    int klen = K / gridDim.z;
    int kbeg = blockIdx.z * klen;
    int NT = klen >> 6;
    int wave = tid >> 6, lane = tid & 63;
    int l16 = lane & 15, quad = lane >> 4;
    int wr = wave >> 2, wc = wave & 3;          // 2 x 4 wave grid
    int lrow = lane >> 3, lcol = lane & 7;      // staging: 8 rows x 8 chunks(16B)
    int scol = lcol ^ lrow;                     // pre-swizzled source chunk
    int sw = l16 & 7;                           // read-side swizzle key (= row&7)

    f32x4 acc[8][4];
    f32x4 zero4 = {0.f, 0.f, 0.f, 0.f};
#pragma unroll
    for (int i = 0; i < 8; ++i)
#pragma unroll
        for (int j = 0; j < 4; ++j) acc[i][j] = zero4;

    // prologue: stage tile 0 into slot 0 (8 loads/lane)
#pragma unroll
    for (int j = 0; j < 4; ++j) {
        int rbase = (wave * 4 + j) * 8;          // wave-uniform, 8-aligned
        GLL16(A + (size_t)(m0 + rbase + lrow) * K + kbeg + scol * 8, &Ash[0][rbase * 64]);
        GLL16(B + (size_t)(n0 + rbase + lrow) * K + kbeg + scol * 8, &Bsh[0][rbase * 64]);
    }

    for (int t = 0; t < NT; ++t) {
        int s = t & 1;
        if (t + 1 < NT) {                        // issue next tile into other slot
            size_t ka = (size_t)kbeg + (size_t)(t + 1) * 64;
            int s2 = s ^ 1;
#pragma unroll
            for (int j = 0; j < 4; ++j) {
                int rbase = (wave * 4 + j) * 8;
                GLL16(A + (size_t)(m0 + rbase + lrow) * K + ka + scol * 8, &Ash[s2][rbase * 64]);
                GLL16(B + (size_t)(n0 + rbase + lrow) * K + ka + scol * 8, &Bsh[s2][rbase * 64]);
            }
            __builtin_amdgcn_sched_barrier(0);
            asm volatile("s_waitcnt vmcnt(8)" ::: "memory");   // tile t landed; 8 in flight
        } else {
            __builtin_amdgcn_sched_barrier(0);
            asm volatile("s_waitcnt vmcnt(0)" ::: "memory");   // last tile: drain once
        }
        __builtin_amdgcn_sched_barrier(0);
        __builtin_amdgcn_s_barrier();            // all waves: tile t visible
        __builtin_amdgcn_sched_barrier(0);

#pragma unroll
        for (int kc = 0; kc < 2; ++kc) {
            f16x8 af[8], bv[4];
#pragma unroll
            for (int i = 0; i < 8; ++i)
                af[i] = *(const f16x8*)&Ash[s][(wr * 128 + i * 16 + l16) * 64
                                              + (((kc * 4 + quad) ^ sw) << 3)];
#pragma unroll
            for (int j = 0; j < 4; ++j)
                bv[j] = *(const f16x8*)&Bsh[s][(wc * 64 + j * 16 + l16) * 64
                                              + (((kc * 4 + quad) ^ sw) << 3)];
            __builtin_amdgcn_s_setprio(1);
#pragma unroll
            for (int i = 0; i < 8; ++i)
#pragma unroll
                for (int j = 0; j < 4; ++j)
                    acc[i][j] = __builtin_amdgcn_mfma_f32_16x16x32_f16(af[i], bv[j], acc[i][j], 0, 0, 0);
            __builtin_amdgcn_s_setprio(0);
        }
        __builtin_amdgcn_sched_barrier(0);
        __builtin_amdgcn_s_barrier();            // reads done: slot s safe to overwrite
        __builtin_amdgcn_sched_barrier(0);
    }

    float* dst = (blockIdx.z == 0) ? C : Cp;
    bool addb = (bias != nullptr) && (blockIdx.z == 0);
#pragma unroll
    for (int i = 0; i < 8; ++i)
#pragma unroll
        for (int r = 0; r < 4; ++r) {
            int row = m0 + wr * 128 + i * 16 + quad * 4 + r;
#pragma unroll
            for (int j = 0; j < 4; ++j) {
                int col = n0 + wc * 64 + j * 16 + l16;
                float v = acc[i][j][r];
                if (addb) v += bias[col];
                dst[(size_t)row * N + col] = v;
            }
        }
}

// ---- out += partial (fp32, float4) ----
__global__ void k_reduce(float* __restrict__ out, const float* __restrict__ part, int n4) {
    int i = blockIdx.x * 256 + threadIdx.x;
    if (i >= n4) return;
    float4 a = ((const float4*)out)[i];
    float4 b = ((const float4*)part)[i];
    a.x += b.x; a.y += b.y; a.z += b.z; a.w += b.w;
    ((float4*)out)[i] = a;
}

// ---- fused RoPE + V-transpose (disjoint column ranges of Y) ----
__global__ __launch_bounds__(256) void k_ropevt(const float* __restrict__ Y,
                                                const float* __restrict__ Yp,
                                                const int* __restrict__ pos,
                                                u16* __restrict__ Qh, u16* __restrict__ Ql,
                                                u16* __restrict__ Kh,
                                                u16* __restrict__ Vt) {
    int tid = threadIdx.x;
    if (blockIdx.x < 2048) {
        __shared__ double finv[64];
        if (tid < 64)   // inv_freq = theta^(-i/64) = 2^(-i*log2(1e6)/64)
            finv[tid] = exp2(-0.3114307588956902 * (double)tid);
        __syncthreads();
        int s = blockIdx.x;
        double p = (double)pos[s];
        const float* y  = Y + (size_t)s * NQKV;
        const float* yp = Yp ? (Yp + (size_t)s * NQKV) : nullptr;
        const float QSCALE = 0.1275174313f;     // (1/sqrt(128)) * log2(e)
        for (int u = tid; u < 2048; u += 256) {
            int blk = u >> 6, i = u & 63;
            int idx  = blk * 128 + i;
            int idx2 = idx + 64;
            double ang = p * finv[i];
            double n = rint(ang * 0.15915494309189535);          // /(2*pi)
            float r = (float)fma(-6.283185307179586, n, ang);    // range-reduced angle
            float sn, cs;
            __sincosf(r, &sn, &cs);
            float v1 = y[idx], v2 = y[idx2];
            if (yp) { v1 += yp[idx]; v2 += yp[idx2]; }
            float o1 = v1 * cs - v2 * sn;
            float o2 = v2 * cs + v1 * sn;
            if (idx < 3584) {
                u16 hh, ll;
                split2(o1 * QSCALE, hh, ll);
                Qh[(size_t)s * 3584 + idx] = hh;
                Ql[(size_t)s * 3584 + idx] = ll;
                split2(o2 * QSCALE, hh, ll);
                Qh[(size_t)s * 3584 + idx2] = hh;
                Ql[(size_t)s * 3584 + idx2] = ll;
            } else {
                Kh[(size_t)s * 512 + (idx  - 3584)] = f2h(o1);
                Kh[(size_t)s * 512 + (idx2 - 3584)] = f2h(o2);
            }
        }
    } else {
        __shared__ __attribute__((aligned(16))) u16 T[64][72];
        int local = blockIdx.x - 2048;
        int s0 = (local % 32) * 64, d0 = (local / 32) * 64;
#pragma unroll
        for (int t = 0; t < 16; ++t) {
            int idx = tid + t * 256;
            int r = idx >> 6, c = idx & 63;
            size_t goff = (size_t)(s0 + r) * NQKV + 4096 + d0 + c;
            float val = Y[goff];
            if (Yp) val += Yp[goff];
            T[c][r] = f2h(val);
        }
        __syncthreads();
#pragma unroll
        for (int t = 0; t < 2; ++t) {
            int cc = tid + t * 256;
            int dr = cc >> 3, s8 = (cc & 7) << 3;
            *(u16x8*)(Vt + (size_t)(d0 + dr) * Sq + s0 + s8) = *(const u16x8*)&T[dr][s8];
        }
    }
}

// ---- flash attention fp16: persistent blocks, LPT queue, reg-prefetch ----
// EXACT R7-verified body (121us, VGPR 124, 4 blocks/CU). Lessons pinned:
//  R3: no min-waves clamp. R5: no device fences in-loop. R8: staging is
//  software prefetch, keep it. R9: VGPR=124 is 4 below the 128 cliff --
//  do not add registers.
__global__ __launch_bounds__(256) void k_attn(const u16* __restrict__ Qh,
                                              const u16* __restrict__ Ql,
                                              const u16* __restrict__ Kh,
                                              const u16* __restrict__ Vt,
                                              u16* __restrict__ AO,
                                              int* __restrict__ ctr) {
    __shared__ __attribute__((aligned(16))) u16 Ks[64][128];   // 16384 B, swizzled
    __shared__ __attribute__((aligned(16))) u16 Vs[128][64];   // 16384 B, swizzled
    __shared__ __attribute__((aligned(16))) u16 Ps[4][16][64]; //  8192 B, swizzled

    int tid = threadIdx.x;
    int wave = tid >> 6, lane = tid & 63, l16 = lane & 15, quad = lane >> 4;
    int sw = l16 & 7;                       // read-side swizzle key (= row&7)

    for (;;) {
        __syncthreads();                   // all waves done with prior item
        if (tid == 0) *(int*)&Ks[0][0] = atomicAdd(ctr, 1);
        __syncthreads();
        int item = *(const int*)&Ks[0][0];
        if (item >= 32 * NH) break;        // block-uniform exit
        int qt = 31 - item / NH;           // longest first (LPT)
        int h  = item % NH;
        int q0 = qt * 64;
        int kvh = h / 7;                   // NH/NKV = 7
        __syncthreads();                   // item slot read by all before staging

        const u16* Kbase = Kh + kvh * HD;                  // row stride 512
        const u16* Vbase = Vt + (size_t)(kvh * HD) * Sq;   // row stride Sq

        // Q fragments hi/lo direct from global (A-layout: m=l16, k=quad*8+j)
        f16x8 qfh[4], qfl[4];
        {
            size_t qoff = (size_t)(q0 + wave * 16 + l16) * Hdim + h * HD + quad * 8;
#pragma unroll
            for (int kc = 0; kc < 4; ++kc) {
                qfh[kc] = *(const f16x8*)(Qh + qoff + kc * 32);
                qfl[kc] = *(const f16x8*)(Ql + qoff + kc * 32);
            }
        }

        // initial staging of tile 0 (swizzled writes)
#pragma unroll
        for (int t = 0; t < 4; ++t) {
            int c = tid + t * 256;
            int row = c >> 4, ch = (c & 15) ^ (row & 7);
            *(u16x8*)&Ks[row][ch << 3] = *(const u16x8*)(Kbase + (size_t)row * 512 + ((c & 15) << 3));
        }
#pragma unroll
        for (int t = 0; t < 4; ++t) {
            int c = tid + t * 256;
            int d = c >> 3, ch = (c & 7) ^ (d & 7);
            *(u16x8*)&Vs[d][ch << 3] = *(const u16x8*)(Vbase + (size_t)d * Sq + ((c & 7) << 3));
        }
        __syncthreads();

        f32x4 O[8];
        f32x4 zero4 = {0.f, 0.f, 0.f, 0.f};
#pragma unroll
        for (int t = 0; t < 8; ++t) O[t] = zero4;
        float mrow[4], lrow[4];
#pragma unroll
        for (int r = 0; r < 4; ++r) { mrow[r] = -1e30f; lrow[r] = 0.f; }

        for (int kt = 0; kt <= qt; ++kt) {
            int k0 = kt * 64;
            int kn = (kt < qt) ? k0 + 64 : k0;     // clamped prefetch base

            // ---- issue next-tile loads into registers (latency overlapped) ----
            u16x8 nk[4], nv[4];
#pragma unroll
            for (int t = 0; t < 4; ++t) {
                int c = tid + t * 256;
                nk[t] = *(const u16x8*)(Kbase + (size_t)(kn + (c >> 4)) * 512 + ((c & 15) << 3));
                nv[t] = *(const u16x8*)(Vbase + (size_t)(c >> 3) * Sq + kn + ((c & 7) << 3));
            }

            // ---- compute current tile from LDS (log2-domain scores) ----
            f32x4 sa[4];                       // S = Q K^T, 2-term split
            __builtin_amdgcn_s_setprio(1);
#pragma unroll
            for (int ct = 0; ct < 4; ++ct) {
                f32x4 z = zero4;
#pragma unroll
                for (int kc = 0; kc < 4; ++kc) {
                    f16x8 b = *(const f16x8*)&Ks[ct * 16 + l16][(((kc * 4 + quad) ^ sw)) << 3];
                    z = __builtin_amdgcn_mfma_f32_16x16x32_f16(qfh[kc], b, z, 0, 0, 0);
                    z = __builtin_amdgcn_mfma_f32_16x16x32_f16(qfl[kc], b, z, 0, 0, 0);
                }
                sa[ct] = z;
            }
            __builtin_amdgcn_s_setprio(0);
            if (kt == qt) {
#pragma unroll
                for (int ct = 0; ct < 4; ++ct)
#pragma unroll
                    for (int r = 0; r < 4; ++r)
                        if (k0 + ct * 16 + l16 > q0 + wave * 16 + quad * 4 + r) sa[ct][r] = -1e30f;
            }
            // row max of this tile
            float pmax[4];
#pragma unroll
            for (int r = 0; r < 4; ++r) {
                float mx = fmaxf(fmaxf(sa[0][r], sa[1][r]), fmaxf(sa[2][r], sa[3][r]));
#pragma unroll
                for (int off = 1; off < 16; off <<= 1)
                    mx = fmaxf(mx, __shfl_xor(mx, off, 64));
                pmax[r] = mx;
            }
            // T13 defer-max: skip rescale while max growth <= 8 (P <= 2^8)
            bool keep = (pmax[0] <= mrow[0] + 8.f) && (pmax[1] <= mrow[1] + 8.f) &&
                        (pmax[2] <= mrow[2] + 8.f) && (pmax[3] <= mrow[3] + 8.f);
            if (!__all(keep)) {
#pragma unroll
                for (int r = 0; r < 4; ++r) {
                    float mnew = fmaxf(mrow[r], pmax[r]);
                    float alpha = exp2f(mrow[r] - mnew);
                    mrow[r] = mnew;
                    lrow[r] *= alpha;
#pragma unroll
                    for (int ct = 0; ct < 8; ++ct) O[ct][r] *= alpha;
                }
            }
            float rs[4] = {0.f, 0.f, 0.f, 0.f};
#pragma unroll
            for (int ct = 0; ct < 4; ++ct)
#pragma unroll
                for (int r = 0; r < 4; ++r) {
                    float p = exp2f(sa[ct][r] - mrow[r]);
                    rs[r] += p;
                    // swizzled Ps write: chunk ^= row&7, row = quad*4+r
                    Ps[wave][quad * 4 + r][(ct * 16 + l16) ^ (((quad * 4 + r) & 7) << 3)] = f2h(p);
                }
#pragma unroll
            for (int r = 0; r < 4; ++r) {
#pragma unroll
                for (int off = 1; off < 16; off <<= 1)
                    rs[r] += __shfl_xor(rs[r], off, 64);
                lrow[r] += rs[r];
            }
            __builtin_amdgcn_s_setprio(1);
#pragma unroll
            for (int kc = 0; kc < 2; ++kc) {   // PV from LDS (Ps wave-private)
                f16x8 a = *(const f16x8*)&Ps[wave][l16][(((kc * 4 + quad) ^ sw)) << 3];
#pragma unroll
                for (int ct = 0; ct < 8; ++ct) {
                    f16x8 b = *(const f16x8*)&Vs[ct * 16 + l16][(((kc * 4 + quad) ^ sw)) << 3];
                    O[ct] = __builtin_amdgcn_mfma_f32_16x16x32_f16(a, b, O[ct], 0, 0, 0);
                }
            }
            __builtin_amdgcn_s_setprio(0);

            // ---- commit prefetched tile to LDS (swizzled) ----
            __syncthreads();                   // all waves done reading Ks/Vs
#pragma unroll
            for (int t = 0; t < 4; ++t) {
                int c = tid + t * 256;
                int row = c >> 4, chk = ((c & 15) ^ (row & 7));
                int d = c >> 3, chv = ((c & 7) ^ (d & 7));
                *(u16x8*)&Ks[row][chk << 3] = nk[t];
                *(u16x8*)&Vs[d][chv << 3]   = nv[t];
            }
            __syncthreads();                   // staged data visible
        }
#pragma unroll
        for (int r = 0; r < 4; ++r) {
            float inv = 1.f / lrow[r];
            int row = q0 + wave * 16 + quad * 4 + r;
#pragma unroll
            for (int ct = 0; ct < 8; ++ct)
                AO[(size_t)row * 3584 + h * HD + ct * 16 + l16] = f2h(O[ct][r] * inv);
        }
    }
}

extern "C" void kernel_launch(void* const* d_in, const int* in_sizes, int n_in,
                              void* d_out, int out_size, void* d_ws, size_t ws_size,
                              hipStream_t stream) {
    (void)in_sizes; (void)n_in; (void)out_size;
    const float* hidden = (const float*)d_in[0];
    const int*   pos    = (const int*)d_in[1];
    const int*   qw_q = (const int*)d_in[2];
    const int*   qz_q = (const int*)d_in[3];
    const float* sc_q = (const float*)d_in[4];
    const float* b_q  = (const float*)d_in[5];
    const int*   qw_k = (const int*)d_in[6];
    const int*   qz_k = (const int*)d_in[7];
    const float* sc_k = (const float*)d_in[8];
    const float* b_k  = (const float*)d_in[9];
    const int*   qw_v = (const int*)d_in[10];
    const int*   qz_v = (const int*)d_in[11];
    const float* sc_v = (const float*)d_in[12];
    const float* b_v  = (const float*)d_in[13];
    const int*   qw_o = (const int*)d_in[14];
    const int*   qz_o = (const int*)d_in[15];
    const float* sc_o = (const float*)d_in[16];
    float* out = (float*)d_out;

    char* base = (char*)d_ws;
    size_t off = 0;
    auto alloc = [&](size_t bytes) {
        char* p = base + off;
        off += (bytes + 255) & ~(size_t)255;
        return p;
    };
    u16* Wh = (u16*)alloc((size_t)NQKV * KD * 2);   // 33.0 MB (reused for W_o fallback)
    u16* Xh = (u16*)alloc((size_t)Sq * Hdim * 2);   // 14.7 MB (reused as Qh, then partial)
    u16* Xl = (u16*)alloc((size_t)Sq * Hdim * 2);   // 14.7 MB (Ql, then partial)
    float* Y = (float*)alloc((size_t)Sq * NQKV * 4);// 37.7 MB (reused for AO)
    u16* Khb = (u16*)alloc((size_t)Sq * 512 * 2);   //  2.1 MB
    u16* Vt  = (u16*)alloc((size_t)512 * Sq * 2);   //  2.1 MB
    float* biasc = (float*)alloc(NQKV * 4);
    int*   ctr   = (int*)alloc(4096);               // attn work-queue counter
    float* Part1 = (float*)alloc((size_t)Sq * NQKV * 4);   // 37.7 MB (unused; layout kept)
    (void)Part1;
    u16* Wo2 = (u16*)alloc((size_t)3584 * KD * 2);  // 25.7 MB (deq_o target in k_pre)
    bool deep2 = (off <= ws_size);
    u16* Qhb = Xh;                 // Xh dead after GEMM1
    u16* Qlb = Xl;
    u16* AO  = (u16*)Y;            // Y dead after rope/vtrans
    u16* Wo  = Wh;                 // Wh dead after GEMM1 (fallback W_o dst)
    float* Part = (float*)Xh;      // Xh+Xl contiguous = 29.4 MB, dead after attn

    hipMemsetAsync(ctr, 0, 4096, stream);           // ws is re-poisoned each call
    // fused preprocessing: cvt(3584) | bias(18) | deq_q(3136) | deq_k(448)
    //                    | deq_v(448) | deq_o(3136, only if deep2)
    int preBlocks = 3584 + 18 + 3136 + 448 + 448 + (deep2 ? 3136 : 0);
    k_pre<<<preBlocks, 256, 0, stream>>>(hidden, Xh, b_q, b_k, b_v, biasc,
                                         qw_q, qz_q, sc_q, qw_k, qz_k, sc_k,
                                         qw_v, qz_v, sc_v, qw_o, qz_o, sc_o,
                                         Wh, deep2 ? Wo2 : nullptr);
    // GEMM1: 256^2 tile, z=1 (144 blocks) -> no partial, rope reads Y only.
    k_gemm256<<<dim3(NQKV / 256, Sq / 256, 1), 512, 0, stream>>>(Xh, Wh, biasc, Y, nullptr, Sq, NQKV, KD);
    k_ropevt<<<2304, 256, 0, stream>>>(Y, nullptr, pos, Qhb, Qlb, Khb, Vt);
    if (!deep2)   // fallback: dequant W_o into Wh after GEMM1 consumed it
        k_dequant<<<dim3(56, 56), 256, 0, stream>>>(qw_o, qz_o, sc_o, Wo, 3584);
    k_attn<<<dim3(1024), 256, 0, stream>>>(Qhb, Qlb, Khb, Vt, AO, ctr);
    // GEMM2: 256^2 tile, split-K=2 (224 blocks, all resident) + reduce.
    k_gemm256<<<dim3(Hdim / 256, Sq / 256, 2), 512, 0, stream>>>(AO, deep2 ? Wo2 : Wo, nullptr, out, Part, Sq, Hdim, KD);
    k_reduce<<<(Sq * Hdim / 4 + 255) / 256, 256, 0, stream>>>(out, Part, Sq * Hdim / 4);
}